// Round 10
// baseline (736.730 us; speedup 1.0000x reference)
//
#include <hip/hip_runtime.h>
#include <math.h>

// Problem constants
#define T_STEPS 256
#define BB 8
#define NSTATE 64
#define DD 80
#define PP 256
#define HH 512
#define OO 512
#define NPARAM 161   // 2*D+1
#define PLS 171      // padded row stride for params in LDS (bank spread)
#define NEG_INF_F (-1000000.0f)

#define GSTR 88      // gemm_mfma LDS row stride in ushorts

typedef __attribute__((ext_vector_type(8))) short s16x8;
typedef __attribute__((ext_vector_type(4))) float f32x4;
typedef _Float16 h2t __attribute__((ext_vector_type(2)));

union PairU { double d; float f[2]; unsigned u[2]; };

__device__ __forceinline__ float sigmoidf_(float x) { return 1.0f / (1.0f + __expf(-x)); }
__device__ __forceinline__ unsigned short bf16rne(float x) {
  union { float f; unsigned u; } v; v.f = x;
  unsigned r = (v.u + 0x7FFFu + ((v.u >> 16) & 1u)) >> 16;
  return (unsigned short)r;
}
__device__ __forceinline__ float bf2f(unsigned s) {
  union { unsigned u; float f; } v; v.u = s << 16; return v.f;
}
__device__ __forceinline__ float fdot2_(unsigned a, unsigned b, float c) {
  union { unsigned u; h2t h; } ua, ub; ua.u = a; ub.u = b;
  return __builtin_amdgcn_fdot2(ua.h, ub.h, c, false);
}
__device__ __forceinline__ unsigned packf16(float a, float b) {
  union { unsigned u; _Float16 f[2]; } p;
  p.f[0] = (_Float16)a; p.f[1] = (_Float16)b;
  return p.u;
}

// ---------------------------------------------------------------------------
// fused conversion/prep kernel. Segments over a grand linear index:
//  s0 w_ih16  [0,262144)          fp16-pair pack of w_ih rows (uint)
//  s1 w1hb    [262144,524288)     bf16 of out_w1[:, 0:512]
//  s2 w1eb    [524288,786432)     bf16 of out_w1[:, 512:1024]
//  s3 inputsb [786432,1048576)    bf16 linear of inputs
//  s4 w2b     [1048576,1114112)   bf16 linear of prenet_w2 [256][256]
//  s5 w1b     [1114112,1146880)   bf16 [256][128] zero-K-padded prenet_w1
//  s6 w2frag  [1146880,1245184)   MFMA B-fragments of out_w2 (verified)
//  s7 whh16   [1245184,1769472)   fp16-pair pack of w_hh rows (uint)
//  s8 hm      [1769472,1785856)   mailbox ring clear (float)
//  s9 arb     [1785856,2048000)   bf16 zero-K-padded AR input [2048][128]
// ---------------------------------------------------------------------------
__global__ __launch_bounds__(256)
void conv_all(const float* __restrict__ w_ih, const float* __restrict__ out_w1,
              const float* __restrict__ inputs, const float* __restrict__ pw2,
              const float* __restrict__ pw1, const float* __restrict__ w2,
              const float* __restrict__ w_hh, const float* __restrict__ mels,
              unsigned* __restrict__ w_ih16, unsigned short* __restrict__ w1hb,
              unsigned short* __restrict__ w1eb, unsigned short* __restrict__ inputsb,
              unsigned short* __restrict__ w2b, unsigned short* __restrict__ w1b,
              unsigned short* __restrict__ w2frag, unsigned* __restrict__ whh16,
              float* __restrict__ hmf, unsigned short* __restrict__ arb)
{
  int idx = blockIdx.x * 256 + threadIdx.x;
  if (idx < 262144) {
    int r = idx >> 7, pp = idx & 127;
    const float* src = &w_ih[(size_t)r * 256 + pp * 2];
    w_ih16[idx] = packf16(src[0], src[1]);
  } else if (idx < 524288) {
    int i = idx - 262144; int r = i >> 9, c = i & 511;
    w1hb[i] = bf16rne(out_w1[(size_t)r * 1024 + c]);
  } else if (idx < 786432) {
    int i = idx - 524288; int r = i >> 9, c = i & 511;
    w1eb[i] = bf16rne(out_w1[(size_t)r * 1024 + 512 + c]);
  } else if (idx < 1048576) {
    int i = idx - 786432;
    inputsb[i] = bf16rne(inputs[i]);
  } else if (idx < 1114112) {
    int i = idx - 1048576;
    w2b[i] = bf16rne(pw2[i]);
  } else if (idx < 1146880) {
    int i = idx - 1114112; int r = i >> 7, c = i & 127;
    w1b[i] = (c < DD) ? bf16rne(pw1[r * DD + c]) : (unsigned short)0;
  } else if (idx < 1245184) {
    int i = idx - 1146880;
    int j = i & 7, lane = (i >> 3) & 63, nt = (i >> 9) % 12, kb = i / 6144;
    int p = nt * 16 + (lane & 15);
    int o = kb * 32 + ((lane >> 4) << 3) + j;
    float v = (p < NPARAM) ? w2[p * OO + o] : 0.0f;
    w2frag[i] = bf16rne(v);
  } else if (idx < 1769472) {
    int i = idx - 1245184;                 // uint index: row*256 + pair
    int gr = i >> 8, pp = i & 255;
    const float* src = &w_hh[(size_t)gr * HH + pp * 2];
    whh16[i] = packf16(src[0], src[1]);
  } else if (idx < 1785856) {
    hmf[idx - 1769472] = 0.0f;             // mailbox ring
  } else if (idx < 2048000) {
    int i = idx - 1785856;
    int c = i & 127; int r = i >> 7; int b = r & 7; int t = r >> 3;
    float v = (t == 0 || c >= DD) ? 0.0f : mels[(b * DD + c) * T_STEPS + (t - 1)];
    arb[i] = bf16rne(v);
  }
}

// ---------------------------------------------------------------------------
// bf16 MFMA GEMM (fragment conventions verified by outnet).
// obf=1: emit bf16 (ushort) C; else fp32.
// ---------------------------------------------------------------------------
__global__ __launch_bounds__(256)
void gemm_mfma(const unsigned short* __restrict__ A, int lda,
               const unsigned short* __restrict__ B, int ldb,
               const float* __restrict__ bias1, const float* __restrict__ bias2,
               void* __restrict__ Cout, int N, int K, int relu, int obf)
{
  __shared__ unsigned short As[64 * GSTR];
  __shared__ unsigned short Bs[64 * GSTR];
  const int tid = threadIdx.x;
  const int lane = tid & 63, wv = tid >> 6;
  const int m0 = blockIdx.y * 64, n0 = blockIdx.x * 64;
  const int srow = tid >> 3, scol = (tid & 7) * 8;

  f32x4 acc[4];
#pragma unroll
  for (int m = 0; m < 4; ++m) acc[m] = (f32x4){0.f, 0.f, 0.f, 0.f};

  for (int k0 = 0; k0 < K; k0 += 64) {
    __syncthreads();
    *(float4*)&As[srow * GSTR + scol] =
        *(const float4*)&A[(size_t)(m0 + srow) * lda + k0 + scol];
    *(float4*)&As[(srow + 32) * GSTR + scol] =
        *(const float4*)&A[(size_t)(m0 + srow + 32) * lda + k0 + scol];
    *(float4*)&Bs[srow * GSTR + scol] =
        *(const float4*)&B[(size_t)(n0 + srow) * ldb + k0 + scol];
    *(float4*)&Bs[(srow + 32) * GSTR + scol] =
        *(const float4*)&B[(size_t)(n0 + srow + 32) * ldb + k0 + scol];
    __syncthreads();
#pragma unroll
    for (int ks = 0; ks < 2; ++ks) {
      const int kk = ks * 32 + 8 * (lane >> 4);
      s16x8 bfr = *(const s16x8*)&Bs[(wv * 16 + (lane & 15)) * GSTR + kk];
#pragma unroll
      for (int m = 0; m < 4; ++m) {
        s16x8 afr = *(const s16x8*)&As[(m * 16 + (lane & 15)) * GSTR + kk];
        acc[m] = __builtin_amdgcn_mfma_f32_16x16x32_bf16(afr, bfr, acc[m], 0, 0, 0);
      }
    }
  }
  const int cn = n0 + wv * 16 + (lane & 15);
  float bj = 0.f;
  if (bias1) bj += bias1[cn];
  if (bias2) bj += bias2[cn];
  const int rbase = m0 + (lane >> 4) * 4;
#pragma unroll
  for (int m = 0; m < 4; ++m)
#pragma unroll
    for (int r = 0; r < 4; ++r) {
      float v = acc[m][r] + bj;
      if (relu) v = fmaxf(v, 0.f);
      size_t ci = (size_t)(rbase + m * 16 + r) * N + cn;
      if (obf) ((unsigned short*)Cout)[ci] = bf16rne(v);
      else     ((float*)Cout)[ci] = v;
    }
}

// ---------------------------------------------------------------------------
// persistent sequential LSTM v10: v9's verified agent-scope tagged mailbox +
// gates GEMM folded into the poll slack. Per step each block computes its own
// 128 gate-x values (w_ih quarter-rows in 32 VGPRs x p2 row staged to LDS
// under the poll) — the 2048x2048 gates GEMM dispatch is eliminated.
// 512 threads, 2 barriers/step. Mailbox unchanged (ring depth 4, cleared by
// conv_all each launch; thread<256 spins on its own tagged word).
// ---------------------------------------------------------------------------
__global__ __launch_bounds__(512)
void lstm_seq(const unsigned* __restrict__ whh16, const unsigned* __restrict__ w_ih16,
              const unsigned short* __restrict__ p2b,
              const float* __restrict__ b_ih, const float* __restrict__ b_hh,
              unsigned short* __restrict__ h_allb, double* __restrict__ hm)
{
  __shared__ unsigned hl16[256];   // h[t-1] as 256 fp16-pairs
  __shared__ unsigned hp2[128];    // p2[t,b] as 128 fp16-pairs
  __shared__ float red[4][128];    // k-quarter partial sums per row
  const int tid = threadIdx.x;
  const int b = blockIdx.x & 7;       // batch group
  const int s = blockIdx.x >> 3;      // j-slice 0..15 (32 units)
  const int j0 = s * 32;
  const int row = tid & 127;          // g*32+jl
  const int kq  = tid >> 7;           // k-quarter 0..3
  const int g = row >> 5, jl = row & 31;
  const int gr = g * HH + j0 + jl;    // global gate-row

  // weights -> VGPRs: recurrent quarter (64 pairs) + input quarter (32 pairs)
  unsigned wreg[64], wxreg[32];
  {
    const unsigned* wp = &whh16[(size_t)gr * 256 + kq * 64];
#pragma unroll
    for (int c = 0; c < 64; ++c) wreg[c] = wp[c];
    const unsigned* wx = &w_ih16[(size_t)gr * 128 + kq * 32];
#pragma unroll
    for (int c = 0; c < 32; ++c) wxreg[c] = wx[c];
  }
  // update-wave biases (b_ih + b_hh per gate-row)
  float bgi[4] = {0.f, 0.f, 0.f, 0.f};
  if (tid < 32) {
#pragma unroll
    for (int gg = 0; gg < 4; ++gg)
      bgi[gg] = b_ih[gg * HH + j0 + tid] + b_hh[gg * HH + j0 + tid];
  }
  float c_reg = 0.f;

  for (int t = 0; t < T_STEPS; ++t) {
    // issue p2-row loads (independent of poll; completes under the spin)
    unsigned short pv0 = 0, pv1 = 0;
    if (tid < 128) {
      const unsigned short* pp = &p2b[((size_t)t * BB + b) * 256 + tid * 2];
      pv0 = pp[0]; pv1 = pp[1];
    }

    // ---- acquire h[t-1]: tid<256 spins on its own tagged word ----
    if (t == 0) {
      if (tid < 256) hl16[tid] = 0u;
    } else if (tid < 256) {
      const double* ring = hm + ((size_t)((t - 1) & 3) * BB + b) * 256;
      PairU w;
      for (;;) {
        w.d = __hip_atomic_load(&ring[tid], __ATOMIC_RELAXED, __HIP_MEMORY_SCOPE_AGENT);
        if (w.u[1] == (unsigned)t) break;
        __builtin_amdgcn_s_sleep(1);
      }
      hl16[tid] = w.u[0];
    }
    if (tid < 128) hp2[tid] = packf16(bf2f(pv0), bf2f(pv1));
    __syncthreads();   // barrier 1: h + p2 ready

    // ---- matvec: recurrent (64 fdot2) + input-gates (32 fdot2) ----
    float a0 = 0.f, a1 = 0.f, a2 = 0.f, a3 = 0.f;
    const unsigned* hp = &hl16[kq * 64];
#pragma unroll
    for (int c = 0; c < 64; c += 4) {
      a0 = fdot2_(wreg[c + 0], hp[c + 0], a0);
      a1 = fdot2_(wreg[c + 1], hp[c + 1], a1);
      a2 = fdot2_(wreg[c + 2], hp[c + 2], a2);
      a3 = fdot2_(wreg[c + 3], hp[c + 3], a3);
    }
    const unsigned* xp = &hp2[kq * 32];
#pragma unroll
    for (int c = 0; c < 32; c += 4) {
      a0 = fdot2_(wxreg[c + 0], xp[c + 0], a0);
      a1 = fdot2_(wxreg[c + 1], xp[c + 1], a1);
      a2 = fdot2_(wxreg[c + 2], xp[c + 2], a2);
      a3 = fdot2_(wxreg[c + 3], xp[c + 3], a3);
    }
    red[kq][row] = (a0 + a1) + (a2 + a3);
    __syncthreads();   // barrier 2: partials ready

    // ---- update wave: reduce + gates + publish (no 3rd barrier) ----
    if (tid < 32) {
      float iv = red[0][tid]      + red[1][tid]      + red[2][tid]      + red[3][tid]      + bgi[0];
      float fv = red[0][32 + tid] + red[1][32 + tid] + red[2][32 + tid] + red[3][32 + tid] + bgi[1];
      float gv = red[0][64 + tid] + red[1][64 + tid] + red[2][64 + tid] + red[3][64 + tid] + bgi[2];
      float ov = red[0][96 + tid] + red[1][96 + tid] + red[2][96 + tid] + red[3][96 + tid] + bgi[3];
      float ct = sigmoidf_(fv) * c_reg + sigmoidf_(iv) * tanhf(gv);
      c_reg = ct;
      float h = sigmoidf_(ov) * tanhf(ct);
      float hpart = __shfl_xor(h, 1);   // partner unit jl^1
      if ((tid & 1) == 0) {
        PairU pv;
        pv.u[0] = packf16(h, hpart);
        pv.u[1] = (unsigned)(t + 1);
        __hip_atomic_store(&hm[((size_t)(t & 3) * BB + b) * 256 + s * 16 + (tid >> 1)],
                           pv.d, __ATOMIC_RELAXED, __HIP_MEMORY_SCOPE_AGENT);
      }
      h_allb[((size_t)t * BB + b) * HH + j0 + tid] = bf16rne(h);
    }
    // No trailing barrier: next iteration's hl16/hp2/red writes are fenced by
    // that iteration's barriers (hazard analysis: every read of this step
    // precedes its reader's next barrier crossing, every conflicting write
    // follows the writer's own crossing of the same barrier).
  }
}

// ---------------------------------------------------------------------------
// fused output net + emission, MFMA (verified layout). Block per (t,b).
// Emissions packed into elp float4 {em, lsn, lsp, 0}.
// ---------------------------------------------------------------------------
__global__ __launch_bounds__(256)
void outnet(const float* __restrict__ hv, const float* __restrict__ zi,
            const unsigned short* __restrict__ w2frag, const float* __restrict__ b2,
            const float* __restrict__ mels, const int* __restrict__ inputs_len,
            float* __restrict__ elp)
{
  __shared__ float hvs[OO];
  __shared__ float xts[96];
  __shared__ s16x8 Afr[2][256];
  __shared__ float pl[64 * PLS];
  const int tid = threadIdx.x;
  const int tb = blockIdx.x;
  const int t = tb >> 3, b = tb & 7;
  const int lane = tid & 63, wv = tid >> 6;

  if (tid < 128) *(float4*)&hvs[tid * 4] = *(const float4*)&hv[(size_t)tb * OO + tid * 4];
  if (tid < DD) xts[tid] = mels[(b * DD + tid) * T_STEPS + t];
  __syncthreads();

  const int n_state = wv * 16 + (lane & 15);
  const int osub = (lane >> 4) * 8;
  const float* zbase = zi + (size_t)(b * 64 + n_state) * OO;

  auto genA = [&](int kb, int buf) {
    int ob = kb * 32 + osub;
    float4 z0 = *(const float4*)&zbase[ob];
    float4 z1 = *(const float4*)&zbase[ob + 4];
    float4 h0 = *(const float4*)&hvs[ob];
    float4 h1 = *(const float4*)&hvs[ob + 4];
    s16x8 s;
    s[0] = bf16rne(fmaxf(z0.x + h0.x, 0.f));
    s[1] = bf16rne(fmaxf(z0.y + h0.y, 0.f));
    s[2] = bf16rne(fmaxf(z0.z + h0.z, 0.f));
    s[3] = bf16rne(fmaxf(z0.w + h0.w, 0.f));
    s[4] = bf16rne(fmaxf(z1.x + h1.x, 0.f));
    s[5] = bf16rne(fmaxf(z1.y + h1.y, 0.f));
    s[6] = bf16rne(fmaxf(z1.z + h1.z, 0.f));
    s[7] = bf16rne(fmaxf(z1.w + h1.w, 0.f));
    Afr[buf][tid] = s;
  };
  genA(0, 0);

  f32x4 acc[4][3];
#pragma unroll
  for (int m = 0; m < 4; ++m)
#pragma unroll
    for (int n = 0; n < 3; ++n) acc[m][n] = (f32x4){0.f, 0.f, 0.f, 0.f};

  const unsigned short* bfp = w2frag + ((size_t)(wv * 3) * 64 + lane) * 8;

  for (int kb = 0; kb < 16; ++kb) {
    __syncthreads();
    s16x8 bf[3];
#pragma unroll
    for (int ntl = 0; ntl < 3; ++ntl)
      bf[ntl] = *(const s16x8*)&bfp[(size_t)kb * 6144 + ntl * 512];
    if (kb < 15) genA(kb + 1, (kb + 1) & 1);
    s16x8 af[4];
#pragma unroll
    for (int m = 0; m < 4; ++m) af[m] = Afr[kb & 1][m * 64 + lane];
#pragma unroll
    for (int m = 0; m < 4; ++m)
#pragma unroll
      for (int ntl = 0; ntl < 3; ++ntl)
        acc[m][ntl] = __builtin_amdgcn_mfma_f32_16x16x32_bf16(af[m], bf[ntl], acc[m][ntl], 0, 0, 0);
  }

  const int prow4 = (lane >> 4) * 4;
#pragma unroll
  for (int ntl = 0; ntl < 3; ++ntl) {
    int p = (wv * 3 + ntl) * 16 + (lane & 15);
    if (p < NPARAM) {
      float bb2 = b2[p];
#pragma unroll
      for (int m = 0; m < 4; ++m)
#pragma unroll
        for (int r = 0; r < 4; ++r)
          pl[(m * 16 + prow4 + r) * PLS + p] = acc[m][ntl][r] + bb2;
    }
  }
  __syncthreads();

  const int ne = tid >> 2, dq = tid & 3;
  float s = 0.f;
  for (int d = dq * 20; d < dq * 20 + 20; ++d) {
    float mean = pl[ne * PLS + d];
    float sp   = pl[ne * PLS + 80 + d];
    float x = xts[d];
    float sf = (sp > 20.f) ? sp : log1pf(__expf(sp));
    float sd = fmaxf(sf, 0.001f);
    float zz = (x - mean) / sd;
    s += -0.5f * zz * zz - __logf(sd) - 0.91893853320467274f;
  }
  s += __shfl_xor(s, 1);
  s += __shfl_xor(s, 2);
  if (dq == 0) {
    int ilen = inputs_len[b];
    float tv = pl[ne * PLS + 160];
    float4 o;
    o.x = (ne < ilen) ? s : 0.f;                       // emission (masked)
    o.y = __logf(fmaxf(sigmoidf_(-tv), 1e-4f));        // log sig(-tv)
    o.z = __logf(fmaxf(sigmoidf_(tv), 1e-4f));         // log sig(tv)
    o.w = 0.f;
    *(float4*)&elp[((size_t)tb * NSTATE + ne) * 4] = o;
  }
}

// ---------------------------------------------------------------------------
// sequential HMM forward scan v2 — UNNORMALIZED. Math: logaddexp is
// shift-invariant, so running beta (no per-step logsumexp) satisfies
// beta_t = alpha_t + sum_{tau<=t} log_c_tau; masked lanes (exact NEG_INF)
// never feed valid lanes (leaving reads n-1 < ilen-1 only). Final answer
// = logsumexp(beta[mlen-1]+log_trans_p) = sum_log_c + sum_final_log_c.
// Removes both 64-lane reductions per step (critical path ~5x shorter).
// fp32 drift: beta ~ -100/step -> |beta| < 3e4, ulp 0.004, accum err ~0.03.
// ---------------------------------------------------------------------------
__global__ __launch_bounds__(512)
void hmm_scan(const float* __restrict__ elp, const int* __restrict__ inputs_len,
              const int* __restrict__ mel_lens, float* __restrict__ out)
{
  const int tid = threadIdx.x;
  const int b = tid >> 6, n = tid & 63;
  const int ilen = inputs_len[b], mlen = mel_lens[b];
  const bool mask = n < ilen;
  const float4* e4 = (const float4*)elp;
  const size_t base = (size_t)b * NSTATE + n;
  float beta = 0.f, la = NEG_INF_F, llsp = 0.f;
  float4 cur = e4[base];

  for (int t = 0; t < T_STEPS; ++t) {
    float4 nxt = {0.f, 0.f, 0.f, 0.f};
    if (t + 1 < T_STEPS) nxt = e4[base + (size_t)(t + 1) * BB * NSTATE];
    float e = cur.x, ln_ = cur.y, lp_ = cur.z;
    if (t == 0) {
      beta = ((n == 0) ? 0.f : NEG_INF_F) + e;
    } else {
      float stay = beta + ln_;
      float lvs = beta + lp_;
      float lv = __shfl_up(lvs, 1, 64);
      if (n == 0) lv = NEG_INF_F;
      float mx = fmaxf(stay, lv), mn = fminf(stay, lv);
      float tt = mask ? (mx + log1pf(__expf(mn - mx))) : NEG_INF_F;
      beta = e + tt;
    }
    if (t == mlen - 1) { la = mask ? beta : NEG_INF_F; llsp = lp_; }
    cur = nxt;
  }

  float v = la + ((n == ilen - 1) ? llsp : NEG_INF_F);
  float m = v;
#pragma unroll
  for (int off = 1; off < 64; off <<= 1) m = fmaxf(m, __shfl_xor(m, off));
  float es = __expf(v - m);
#pragma unroll
  for (int off = 1; off < 64; off <<= 1) es += __shfl_xor(es, off);
  if (n == 0) out[b] = m + __logf(es);
}

// ---------------------------------------------------------------------------
extern "C" void kernel_launch(void* const* d_in, const int* in_sizes, int n_in,
                              void* d_out, int out_size, void* d_ws, size_t ws_size,
                              hipStream_t stream)
{
  const float* inputs    = (const float*)d_in[0];
  const float* mels      = (const float*)d_in[1];
  const float* prenet_w1 = (const float*)d_in[2];
  const float* prenet_w2 = (const float*)d_in[3];
  const float* w_ih      = (const float*)d_in[4];
  const float* w_hh      = (const float*)d_in[5];
  const float* b_ih      = (const float*)d_in[6];
  const float* b_hh      = (const float*)d_in[7];
  const float* out_w1    = (const float*)d_in[8];
  const float* out_b1    = (const float*)d_in[9];
  const float* out_w2    = (const float*)d_in[10];
  const float* out_b2    = (const float*)d_in[11];
  const int* inputs_len  = (const int*)d_in[12];
  const int* mel_lens    = (const int*)d_in[13];

  float* ws = (float*)d_ws;
  float* zi      = ws;                        // 262144
  float* hv      = ws + 262144;               // 1048576
  float* elp     = ws + 1310720;              // 524288 (T*B*64 float4)
  double* hm     = (double*)(ws + 1835008);   // 16384 fl = 8192 dbl ring
  unsigned short* w2frag  = (unsigned short*)(ws + 1851392); // 98304 sh
  unsigned short* h_allb  = (unsigned short*)(ws + 1900544); // 1048576 sh
  unsigned short* p2b     = (unsigned short*)(ws + 2424832); // 524288 sh
  unsigned short* p1b     = (unsigned short*)(ws + 2686976); // 524288 sh
  unsigned short* arb     = (unsigned short*)(ws + 2949120); // 262144 sh
  unsigned short* w1b     = (unsigned short*)(ws + 3080192); // 32768 sh
  unsigned short* w2b     = (unsigned short*)(ws + 3096576); // 65536 sh
  unsigned short* w1hb    = (unsigned short*)(ws + 3129344); // 262144 sh
  unsigned short* w1eb    = (unsigned short*)(ws + 3260416); // 262144 sh
  unsigned short* inputsb = (unsigned short*)(ws + 3391488); // 262144 sh
  unsigned* whh16         = (unsigned*)(ws + 3522560);       // 524288 u32
  unsigned* w_ih16        = (unsigned*)(ws + 4046848);       // 262144 u32

  // fused prep (weights, fragments, mailbox clear, arb) — 2048000 items
  conv_all<<<8000, 256, 0, stream>>>(w_ih, out_w1, inputs, prenet_w2, prenet_w1,
                                     out_w2, w_hh, mels, w_ih16, w1hb, w1eb,
                                     inputsb, w2b, w1b, w2frag, whh16,
                                     (float*)hm, arb);

  // prenet (MFMA, bf16 out):  p1 = relu(arb @ w1b^T)  M=2048 N=256 K=128
  gemm_mfma<<<dim3(4, 32), 256, 0, stream>>>(arb, 128, w1b, 128,
                                             nullptr, nullptr, p1b, PP, 128, 1, 1);
  // p2 = relu(p1b @ w2b^T)   K=256
  gemm_mfma<<<dim3(4, 32), 256, 0, stream>>>(p1b, 256, w2b, 256,
                                             nullptr, nullptr, p2b, PP, 256, 1, 1);
  // zi = inputsb @ w1eb^T + b1  (fp32 out)  M=512 N=512 K=512
  gemm_mfma<<<dim3(8, 8), 256, 0, stream>>>(inputsb, 512, w1eb, 512,
                                            out_b1, nullptr, zi, 512, 512, 0, 0);

  // sequential LSTM (gates folded into poll slack; agent-scope mailbox)
  lstm_seq<<<128, 512, 0, stream>>>(whh16, w_ih16, p2b, b_ih, b_hh, h_allb, hm);

  // hv = h_allb @ w1hb^T  (fp32 out)  M=2048 N=512 K=512
  gemm_mfma<<<dim3(8, 32), 256, 0, stream>>>(h_allb, 512, w1hb, 512,
                                             nullptr, nullptr, hv, 512, 512, 0, 0);

  // fused output net + emission (MFMA) -> elp
  outnet<<<2048, 256, 0, stream>>>(hv, zi, w2frag, out_b2, mels, inputs_len, elp);

  // sequential HMM scan (unnormalized)
  hmm_scan<<<1, 512, 0, stream>>>(elp, inputs_len, mel_lens, (float*)d_out);
}

// Round 11
// 659.097 us; speedup vs baseline: 1.1178x; 1.1178x over previous
//
#include <hip/hip_runtime.h>
#include <math.h>

// Problem constants
#define T_STEPS 256
#define BB 8
#define NSTATE 64
#define DD 80
#define PP 256
#define HH 512
#define OO 512
#define NPARAM 161   // 2*D+1
#define PLS 171      // padded row stride for params in LDS (bank spread)
#define NEG_INF_F (-1000000.0f)

#define GSTR 88      // gemm LDS row stride in ushorts

typedef __attribute__((ext_vector_type(8))) short s16x8;
typedef __attribute__((ext_vector_type(4))) float f32x4;
typedef _Float16 h2t __attribute__((ext_vector_type(2)));

union PairU { double d; float f[2]; unsigned u[2]; };

__device__ __forceinline__ float sigmoidf_(float x) { return 1.0f / (1.0f + __expf(-x)); }
__device__ __forceinline__ unsigned short bf16rne(float x) {
  union { float f; unsigned u; } v; v.f = x;
  unsigned r = (v.u + 0x7FFFu + ((v.u >> 16) & 1u)) >> 16;
  return (unsigned short)r;
}
__device__ __forceinline__ float bf2f(unsigned s) {
  union { unsigned u; float f; } v; v.u = s << 16; return v.f;
}
__device__ __forceinline__ float fdot2_(unsigned a, unsigned b, float c) {
  union { unsigned u; h2t h; } ua, ub; ua.u = a; ub.u = b;
  return __builtin_amdgcn_fdot2(ua.h, ub.h, c, false);
}
__device__ __forceinline__ unsigned packf16(float a, float b) {
  union { unsigned u; _Float16 f[2]; } p;
  p.f[0] = (_Float16)a; p.f[1] = (_Float16)b;
  return p.u;
}

// ---------------------------------------------------------------------------
// fused conversion/prep kernel (R9-verified layout). Segments:
//  s0 w_ihb   [0,524288)          bf16 linear of w_ih [2048][256]
//  s1 w1hb    [524288,786432)     bf16 of out_w1[:, 0:512]
//  s2 w1eb    [786432,1048576)    bf16 of out_w1[:, 512:1024]
//  s3 inputsb [1048576,1310720)   bf16 linear of inputs
//  s4 w2b     [1310720,1376256)   bf16 linear of prenet_w2 [256][256]
//  s5 w1b     [1376256,1409024)   bf16 [256][128] zero-K-padded prenet_w1
//  s6 w2frag  [1409024,1507328)   MFMA B-fragments of out_w2 (verified)
//  s7 whh16   [1507328,2031616)   fp16-pair pack of w_hh rows (uint)
//  s8 hm      [2031616,2048000)   mailbox ring clear (float)
//  s9 arb     [2048000,2310144)   bf16 zero-K-padded AR input [2048][128]
// ---------------------------------------------------------------------------
__global__ __launch_bounds__(256)
void conv_all(const float* __restrict__ w_ih, const float* __restrict__ out_w1,
              const float* __restrict__ inputs, const float* __restrict__ pw2,
              const float* __restrict__ pw1, const float* __restrict__ w2,
              const float* __restrict__ w_hh, const float* __restrict__ mels,
              unsigned short* __restrict__ w_ihb, unsigned short* __restrict__ w1hb,
              unsigned short* __restrict__ w1eb, unsigned short* __restrict__ inputsb,
              unsigned short* __restrict__ w2b, unsigned short* __restrict__ w1b,
              unsigned short* __restrict__ w2frag, unsigned* __restrict__ whh16,
              float* __restrict__ hmf, unsigned short* __restrict__ arb)
{
  int idx = blockIdx.x * 256 + threadIdx.x;
  if (idx < 524288) {
    w_ihb[idx] = bf16rne(w_ih[idx]);
  } else if (idx < 786432) {
    int i = idx - 524288; int r = i >> 9, c = i & 511;
    w1hb[i] = bf16rne(out_w1[(size_t)r * 1024 + c]);
  } else if (idx < 1048576) {
    int i = idx - 786432; int r = i >> 9, c = i & 511;
    w1eb[i] = bf16rne(out_w1[(size_t)r * 1024 + 512 + c]);
  } else if (idx < 1310720) {
    int i = idx - 1048576;
    inputsb[i] = bf16rne(inputs[i]);
  } else if (idx < 1376256) {
    int i = idx - 1310720;
    w2b[i] = bf16rne(pw2[i]);
  } else if (idx < 1409024) {
    int i = idx - 1376256; int r = i >> 7, c = i & 127;
    w1b[i] = (c < DD) ? bf16rne(pw1[r * DD + c]) : (unsigned short)0;
  } else if (idx < 1507328) {
    int i = idx - 1409024;
    int j = i & 7, lane = (i >> 3) & 63, nt = (i >> 9) % 12, kb = i / 6144;
    int p = nt * 16 + (lane & 15);
    int o = kb * 32 + ((lane >> 4) << 3) + j;
    float v = (p < NPARAM) ? w2[p * OO + o] : 0.0f;
    w2frag[i] = bf16rne(v);
  } else if (idx < 2031616) {
    int i = idx - 1507328;                 // uint index: row*256 + pair
    int gr = i >> 8, pp = i & 255;
    const float* src = &w_hh[(size_t)gr * HH + pp * 2];
    whh16[i] = packf16(src[0], src[1]);
  } else if (idx < 2048000) {
    hmf[idx - 2031616] = 0.0f;             // mailbox ring
  } else if (idx < 2310144) {
    int i = idx - 2048000;
    int c = i & 127; int r = i >> 7; int b = r & 7; int t = r >> 3;
    float v = (t == 0 || c >= DD) ? 0.0f : mels[(b * DD + c) * T_STEPS + (t - 1)];
    arb[i] = bf16rne(v);
  }
}

// ---------------------------------------------------------------------------
// bf16 MFMA GEMM tile body (fragment conventions verified by outnet).
// obf=1: emit bf16 (ushort) C; else fp32.
// ---------------------------------------------------------------------------
__device__ __forceinline__
void gemm_tile(const unsigned short* __restrict__ A, int lda,
               const unsigned short* __restrict__ B, int ldb,
               const float* __restrict__ bias1, const float* __restrict__ bias2,
               void* __restrict__ Cout, int N, int K, int relu, int obf,
               int m0, int n0, unsigned short* As, unsigned short* Bs)
{
  const int tid = threadIdx.x;
  const int lane = tid & 63, wv = tid >> 6;
  const int srow = tid >> 3, scol = (tid & 7) * 8;

  f32x4 acc[4];
#pragma unroll
  for (int m = 0; m < 4; ++m) acc[m] = (f32x4){0.f, 0.f, 0.f, 0.f};

  for (int k0 = 0; k0 < K; k0 += 64) {
    __syncthreads();
    *(float4*)&As[srow * GSTR + scol] =
        *(const float4*)&A[(size_t)(m0 + srow) * lda + k0 + scol];
    *(float4*)&As[(srow + 32) * GSTR + scol] =
        *(const float4*)&A[(size_t)(m0 + srow + 32) * lda + k0 + scol];
    *(float4*)&Bs[srow * GSTR + scol] =
        *(const float4*)&B[(size_t)(n0 + srow) * ldb + k0 + scol];
    *(float4*)&Bs[(srow + 32) * GSTR + scol] =
        *(const float4*)&B[(size_t)(n0 + srow + 32) * ldb + k0 + scol];
    __syncthreads();
#pragma unroll
    for (int ks = 0; ks < 2; ++ks) {
      const int kk = ks * 32 + 8 * (lane >> 4);
      s16x8 bfr = *(const s16x8*)&Bs[(wv * 16 + (lane & 15)) * GSTR + kk];
#pragma unroll
      for (int m = 0; m < 4; ++m) {
        s16x8 afr = *(const s16x8*)&As[(m * 16 + (lane & 15)) * GSTR + kk];
        acc[m] = __builtin_amdgcn_mfma_f32_16x16x32_bf16(afr, bfr, acc[m], 0, 0, 0);
      }
    }
  }
  const int cn = n0 + wv * 16 + (lane & 15);
  float bj = 0.f;
  if (bias1) bj += bias1[cn];
  if (bias2) bj += bias2[cn];
  const int rbase = m0 + (lane >> 4) * 4;
#pragma unroll
  for (int m = 0; m < 4; ++m)
#pragma unroll
    for (int r = 0; r < 4; ++r) {
      float v = acc[m][r] + bj;
      if (relu) v = fmaxf(v, 0.f);
      size_t ci = (size_t)(rbase + m * 16 + r) * N + cn;
      if (obf) ((unsigned short*)Cout)[ci] = bf16rne(v);
      else     ((float*)Cout)[ci] = v;
    }
}

__global__ __launch_bounds__(256)
void gemm_mfma(const unsigned short* __restrict__ A, int lda,
               const unsigned short* __restrict__ B, int ldb,
               const float* __restrict__ bias1, const float* __restrict__ bias2,
               void* __restrict__ Cout, int N, int K, int relu, int obf)
{
  __shared__ unsigned short As[64 * GSTR];
  __shared__ unsigned short Bs[64 * GSTR];
  gemm_tile(A, lda, B, ldb, bias1, bias2, Cout, N, K, relu, obf,
            blockIdx.y * 64, blockIdx.x * 64, As, Bs);
}

// merged gates (1024 blocks, 32x32 tiles) + zi (64 blocks, 8x8 tiles)
__global__ __launch_bounds__(256)
void gemm_pair(const unsigned short* __restrict__ p2b, const unsigned short* __restrict__ w_ihb,
               const float* __restrict__ b_ih, const float* __restrict__ b_hh,
               unsigned short* __restrict__ gatesb,
               const unsigned short* __restrict__ inputsb, const unsigned short* __restrict__ w1eb,
               const float* __restrict__ out_b1, float* __restrict__ zi)
{
  __shared__ unsigned short As[64 * GSTR];
  __shared__ unsigned short Bs[64 * GSTR];
  int bid = blockIdx.x;
  if (bid < 1024) {
    gemm_tile(p2b, 256, w_ihb, 256, b_ih, b_hh, gatesb, 2048, 256, 0, 1,
              (bid >> 5) * 64, (bid & 31) * 64, As, Bs);
  } else {
    int i = bid - 1024;
    gemm_tile(inputsb, 512, w1eb, 512, out_b1, nullptr, zi, 512, 512, 0, 0,
              (i >> 3) * 64, (i & 7) * 64, As, Bs);
  }
}

// ---------------------------------------------------------------------------
// persistent sequential LSTM (R9-verified): agent-scope tagged mailbox,
// 512 threads, 2 barriers/step. Per batch: 256 words {2xfp16 h, 32b tag},
// ring depth 4, cleared by conv_all each launch. Thread<256 spins on its
// own word; matvec k-quartered (64 fdot2/thread); gate reduction folded
// into the update wave (no 3rd barrier).
// ---------------------------------------------------------------------------
__global__ __launch_bounds__(512)
void lstm_seq(const unsigned* __restrict__ whh16, const unsigned short* __restrict__ gatesb,
              unsigned short* __restrict__ h_allb, double* __restrict__ hm)
{
  __shared__ unsigned hl16[256];   // h[t-1] as 256 fp16-pairs
  __shared__ float red[4][128];    // k-quarter partial sums per row
  const int tid = threadIdx.x;
  const int b = blockIdx.x & 7;       // batch group
  const int s = blockIdx.x >> 3;      // j-slice 0..15 (32 units)
  const int j0 = s * 32;
  const int row = tid & 127;          // g*32+jl
  const int kq  = tid >> 7;           // k-quarter 0..3
  const int g = row >> 5, jl = row & 31;
  const int gr = g * HH + j0 + jl;    // global gate-row

  // weights -> VGPRs: 64 fp16-pairs = 128 k elems (this thread's k-quarter)
  unsigned wreg[64];
  {
    const unsigned* wp = &whh16[(size_t)gr * 256 + kq * 64];
#pragma unroll
    for (int c = 0; c < 64; ++c) wreg[c] = wp[c];
  }
  float c_reg = 0.f;

  for (int t = 0; t < T_STEPS; ++t) {
    // prefetch this thread's 4 gate-x values (tid<32; independent of poll)
    float gxv[4] = {0.f, 0.f, 0.f, 0.f};
    if (tid < 32) {
      const unsigned short* gp = &gatesb[((size_t)t * BB + b) * 2048 + j0 + tid];
#pragma unroll
      for (int gg = 0; gg < 4; ++gg) gxv[gg] = bf2f(gp[gg * HH]);
    }

    // ---- acquire h[t-1]: tid<256 spins on its own tagged word ----
    if (t == 0) {
      if (tid < 256) hl16[tid] = 0u;
    } else if (tid < 256) {
      const double* ring = hm + ((size_t)((t - 1) & 3) * BB + b) * 256;
      PairU w;
      for (;;) {
        w.d = __hip_atomic_load(&ring[tid], __ATOMIC_RELAXED, __HIP_MEMORY_SCOPE_AGENT);
        if (w.u[1] == (unsigned)t) break;
        __builtin_amdgcn_s_sleep(1);
      }
      hl16[tid] = w.u[0];
    }
    __syncthreads();   // barrier 1: h ready

    // ---- matvec: row x 128 k via fdot2, 4 chains of 16 ----
    float a0 = 0.f, a1 = 0.f, a2 = 0.f, a3 = 0.f;
    const unsigned* hp = &hl16[kq * 64];
#pragma unroll
    for (int c = 0; c < 64; c += 4) {
      a0 = fdot2_(wreg[c + 0], hp[c + 0], a0);
      a1 = fdot2_(wreg[c + 1], hp[c + 1], a1);
      a2 = fdot2_(wreg[c + 2], hp[c + 2], a2);
      a3 = fdot2_(wreg[c + 3], hp[c + 3], a3);
    }
    red[kq][row] = (a0 + a1) + (a2 + a3);
    __syncthreads();   // barrier 2: partials ready

    // ---- update wave: 16 red reads + gates + publish (no 3rd barrier) ----
    if (tid < 32) {
      float iv = red[0][tid]       + red[1][tid]       + red[2][tid]       + red[3][tid]       + gxv[0];
      float fv = red[0][32 + tid]  + red[1][32 + tid]  + red[2][32 + tid]  + red[3][32 + tid]  + gxv[1];
      float gv = red[0][64 + tid]  + red[1][64 + tid]  + red[2][64 + tid]  + red[3][64 + tid]  + gxv[2];
      float ov = red[0][96 + tid]  + red[1][96 + tid]  + red[2][96 + tid]  + red[3][96 + tid]  + gxv[3];
      float ct = sigmoidf_(fv) * c_reg + sigmoidf_(iv) * tanhf(gv);
      c_reg = ct;
      float h = sigmoidf_(ov) * tanhf(ct);
      float hpart = __shfl_xor(h, 1);   // partner unit jl^1
      if ((tid & 1) == 0) {
        PairU pv;
        pv.u[0] = packf16(h, hpart);
        pv.u[1] = (unsigned)(t + 1);
        __hip_atomic_store(&hm[((size_t)(t & 3) * BB + b) * 256 + s * 16 + (tid >> 1)],
                           pv.d, __ATOMIC_RELAXED, __HIP_MEMORY_SCOPE_AGENT);
      }
      h_allb[((size_t)t * BB + b) * HH + j0 + tid] = bf16rne(h);
    }
    // No trailing barrier: next iteration's hl16/red writes are fenced by
    // that iteration's barriers (every read of this step precedes its
    // reader's next barrier crossing; every conflicting write follows the
    // writer's own crossing of the same barrier).
  }
}

// ---------------------------------------------------------------------------
// fused output net + emission, MFMA (verified layout). Block per (t,b).
// Emissions packed into elp float4 {em, lsn, lsp, 0}.
// ---------------------------------------------------------------------------
__global__ __launch_bounds__(256)
void outnet(const float* __restrict__ hv, const float* __restrict__ zi,
            const unsigned short* __restrict__ w2frag, const float* __restrict__ b2,
            const float* __restrict__ mels, const int* __restrict__ inputs_len,
            float* __restrict__ elp)
{
  __shared__ float hvs[OO];
  __shared__ float xts[96];
  __shared__ s16x8 Afr[2][256];
  __shared__ float pl[64 * PLS];
  const int tid = threadIdx.x;
  const int tb = blockIdx.x;
  const int t = tb >> 3, b = tb & 7;
  const int lane = tid & 63, wv = tid >> 6;

  if (tid < 128) *(float4*)&hvs[tid * 4] = *(const float4*)&hv[(size_t)tb * OO + tid * 4];
  if (tid < DD) xts[tid] = mels[(b * DD + tid) * T_STEPS + t];
  __syncthreads();

  const int n_state = wv * 16 + (lane & 15);
  const int osub = (lane >> 4) * 8;
  const float* zbase = zi + (size_t)(b * 64 + n_state) * OO;

  auto genA = [&](int kb, int buf) {
    int ob = kb * 32 + osub;
    float4 z0 = *(const float4*)&zbase[ob];
    float4 z1 = *(const float4*)&zbase[ob + 4];
    float4 h0 = *(const float4*)&hvs[ob];
    float4 h1 = *(const float4*)&hvs[ob + 4];
    s16x8 s;
    s[0] = bf16rne(fmaxf(z0.x + h0.x, 0.f));
    s[1] = bf16rne(fmaxf(z0.y + h0.y, 0.f));
    s[2] = bf16rne(fmaxf(z0.z + h0.z, 0.f));
    s[3] = bf16rne(fmaxf(z0.w + h0.w, 0.f));
    s[4] = bf16rne(fmaxf(z1.x + h1.x, 0.f));
    s[5] = bf16rne(fmaxf(z1.y + h1.y, 0.f));
    s[6] = bf16rne(fmaxf(z1.z + h1.z, 0.f));
    s[7] = bf16rne(fmaxf(z1.w + h1.w, 0.f));
    Afr[buf][tid] = s;
  };
  genA(0, 0);

  f32x4 acc[4][3];
#pragma unroll
  for (int m = 0; m < 4; ++m)
#pragma unroll
    for (int n = 0; n < 3; ++n) acc[m][n] = (f32x4){0.f, 0.f, 0.f, 0.f};

  const unsigned short* bfp = w2frag + ((size_t)(wv * 3) * 64 + lane) * 8;

  for (int kb = 0; kb < 16; ++kb) {
    __syncthreads();
    s16x8 bf[3];
#pragma unroll
    for (int ntl = 0; ntl < 3; ++ntl)
      bf[ntl] = *(const s16x8*)&bfp[(size_t)kb * 6144 + ntl * 512];
    if (kb < 15) genA(kb + 1, (kb + 1) & 1);
    s16x8 af[4];
#pragma unroll
    for (int m = 0; m < 4; ++m) af[m] = Afr[kb & 1][m * 64 + lane];
#pragma unroll
    for (int m = 0; m < 4; ++m)
#pragma unroll
      for (int ntl = 0; ntl < 3; ++ntl)
        acc[m][ntl] = __builtin_amdgcn_mfma_f32_16x16x32_bf16(af[m], bf[ntl], acc[m][ntl], 0, 0, 0);
  }

  const int prow4 = (lane >> 4) * 4;
#pragma unroll
  for (int ntl = 0; ntl < 3; ++ntl) {
    int p = (wv * 3 + ntl) * 16 + (lane & 15);
    if (p < NPARAM) {
      float bb2 = b2[p];
#pragma unroll
      for (int m = 0; m < 4; ++m)
#pragma unroll
        for (int r = 0; r < 4; ++r)
          pl[(m * 16 + prow4 + r) * PLS + p] = acc[m][ntl][r] + bb2;
    }
  }
  __syncthreads();

  const int ne = tid >> 2, dq = tid & 3;
  float s = 0.f;
  for (int d = dq * 20; d < dq * 20 + 20; ++d) {
    float mean = pl[ne * PLS + d];
    float sp   = pl[ne * PLS + 80 + d];
    float x = xts[d];
    float sf = (sp > 20.f) ? sp : log1pf(__expf(sp));
    float sd = fmaxf(sf, 0.001f);
    float zz = (x - mean) / sd;
    s += -0.5f * zz * zz - __logf(sd) - 0.91893853320467274f;
  }
  s += __shfl_xor(s, 1);
  s += __shfl_xor(s, 2);
  if (dq == 0) {
    int ilen = inputs_len[b];
    float tv = pl[ne * PLS + 160];
    float4 o;
    o.x = (ne < ilen) ? s : 0.f;                       // emission (masked)
    o.y = __logf(fmaxf(sigmoidf_(-tv), 1e-4f));        // log sig(-tv)
    o.z = __logf(fmaxf(sigmoidf_(tv), 1e-4f));         // log sig(tv)
    o.w = 0.f;
    *(float4*)&elp[((size_t)tb * NSTATE + ne) * 4] = o;
  }
}

// ---------------------------------------------------------------------------
// sequential HMM forward scan — UNNORMALIZED (verified R10, absmax 0.0).
// beta_t = alpha_t + sum log_c (shift-invariance of logaddexp); final answer
// = logsumexp(beta[mlen-1]+log_trans_p). 8 blocks, one wave per batch.
// ---------------------------------------------------------------------------
__global__ __launch_bounds__(64)
void hmm_scan(const float* __restrict__ elp, const int* __restrict__ inputs_len,
              const int* __restrict__ mel_lens, float* __restrict__ out)
{
  const int b = blockIdx.x;
  const int n = threadIdx.x;
  const int ilen = inputs_len[b], mlen = mel_lens[b];
  const bool mask = n < ilen;
  const float4* e4 = (const float4*)elp;
  const size_t base = (size_t)b * NSTATE + n;
  float beta = 0.f, la = NEG_INF_F, llsp = 0.f;
  float4 cur = e4[base];

  for (int t = 0; t < T_STEPS; ++t) {
    float4 nxt = {0.f, 0.f, 0.f, 0.f};
    if (t + 1 < T_STEPS) nxt = e4[base + (size_t)(t + 1) * BB * NSTATE];
    float e = cur.x, ln_ = cur.y, lp_ = cur.z;
    if (t == 0) {
      beta = ((n == 0) ? 0.f : NEG_INF_F) + e;
    } else {
      float stay = beta + ln_;
      float lvs = beta + lp_;
      float lv = __shfl_up(lvs, 1, 64);
      if (n == 0) lv = NEG_INF_F;
      float mx = fmaxf(stay, lv), mn = fminf(stay, lv);
      float tt = mask ? (mx + log1pf(__expf(mn - mx))) : NEG_INF_F;
      beta = e + tt;
    }
    if (t == mlen - 1) { la = mask ? beta : NEG_INF_F; llsp = lp_; }
    cur = nxt;
  }

  float v = la + ((n == ilen - 1) ? llsp : NEG_INF_F);
  float m = v;
#pragma unroll
  for (int off = 1; off < 64; off <<= 1) m = fmaxf(m, __shfl_xor(m, off));
  float es = __expf(v - m);
#pragma unroll
  for (int off = 1; off < 64; off <<= 1) es += __shfl_xor(es, off);
  if (n == 0) out[b] = m + __logf(es);
}

// ---------------------------------------------------------------------------
extern "C" void kernel_launch(void* const* d_in, const int* in_sizes, int n_in,
                              void* d_out, int out_size, void* d_ws, size_t ws_size,
                              hipStream_t stream)
{
  const float* inputs    = (const float*)d_in[0];
  const float* mels      = (const float*)d_in[1];
  const float* prenet_w1 = (const float*)d_in[2];
  const float* prenet_w2 = (const float*)d_in[3];
  const float* w_ih      = (const float*)d_in[4];
  const float* w_hh      = (const float*)d_in[5];
  const float* b_ih      = (const float*)d_in[6];
  const float* b_hh      = (const float*)d_in[7];
  const float* out_w1    = (const float*)d_in[8];
  const float* out_b1    = (const float*)d_in[9];
  const float* out_w2    = (const float*)d_in[10];
  const float* out_b2    = (const float*)d_in[11];
  const int* inputs_len  = (const int*)d_in[12];
  const int* mel_lens    = (const int*)d_in[13];

  float* ws = (float*)d_ws;
  unsigned short* gatesb = (unsigned short*)ws;              // 4194304 sh (2097152 fl)
  float* zi      = ws + 2097152;              // 262144
  float* hv      = ws + 2359296;              // 1048576
  float* elp     = ws + 3407872;              // 524288 (T*B*64 float4)
  double* hm     = (double*)(ws + 3932160);   // 16384 fl = 8192 dbl ring
  unsigned short* w2frag  = (unsigned short*)(ws + 3948544); // 98304 sh
  unsigned short* h_allb  = (unsigned short*)(ws + 3997696); // 1048576 sh
  unsigned short* p2b     = (unsigned short*)(ws + 4521984); // 524288 sh
  unsigned short* p1b     = (unsigned short*)(ws + 4784128); // 524288 sh
  unsigned short* arb     = (unsigned short*)(ws + 5046272); // 262144 sh
  unsigned short* w1b     = (unsigned short*)(ws + 5177344); // 32768 sh
  unsigned short* w2b     = (unsigned short*)(ws + 5193728); // 65536 sh
  unsigned short* w_ihb   = (unsigned short*)(ws + 5226496); // 524288 sh
  unsigned short* w1hb    = (unsigned short*)(ws + 5488640); // 262144 sh
  unsigned short* w1eb    = (unsigned short*)(ws + 5619712); // 262144 sh
  unsigned short* inputsb = (unsigned short*)(ws + 5750784); // 262144 sh
  unsigned* whh16         = (unsigned*)(ws + 5881856);       // 524288 u32

  // fused prep (weights, fragments, mailbox clear, arb) — 2310144 items
  conv_all<<<9024, 256, 0, stream>>>(w_ih, out_w1, inputs, prenet_w2, prenet_w1,
                                     out_w2, w_hh, mels, w_ihb, w1hb, w1eb,
                                     inputsb, w2b, w1b, w2frag, whh16,
                                     (float*)hm, arb);

  // prenet (MFMA, bf16 out):  p1 = relu(arb @ w1b^T)  M=2048 N=256 K=128
  gemm_mfma<<<dim3(4, 32), 256, 0, stream>>>(arb, 128, w1b, 128,
                                             nullptr, nullptr, p1b, PP, 128, 1, 1);
  // p2 = relu(p1b @ w2b^T)   K=256
  gemm_mfma<<<dim3(4, 32), 256, 0, stream>>>(p1b, 256, w2b, 256,
                                             nullptr, nullptr, p2b, PP, 256, 1, 1);
  // merged: gatesb = p2b @ w_ihb^T + b_ih + b_hh (bf16) ; zi = inputsb @ w1eb^T + b1 (fp32)
  gemm_pair<<<1088, 256, 0, stream>>>(p2b, w_ihb, b_ih, b_hh, gatesb,
                                      inputsb, w1eb, out_b1, zi);

  // sequential LSTM (R9-verified mailbox; separate gates)
  lstm_seq<<<128, 512, 0, stream>>>(whh16, gatesb, h_allb, hm);

  // hv = h_allb @ w1hb^T  (fp32 out)  M=2048 N=512 K=512
  gemm_mfma<<<dim3(8, 32), 256, 0, stream>>>(h_allb, 512, w1hb, 512,
                                             nullptr, nullptr, hv, 512, 512, 0, 0);

  // fused output net + emission (MFMA) -> elp
  outnet<<<2048, 256, 0, stream>>>(hv, zi, w2frag, out_b2, mels, inputs_len, elp);

  // sequential HMM scan (unnormalized, 8 blocks)
  hmm_scan<<<8, 64, 0, stream>>>(elp, inputs_len, mel_lens, (float*)d_out);
}

// Round 12
// 554.738 us; speedup vs baseline: 1.3281x; 1.1881x over previous
//
#include <hip/hip_runtime.h>
#include <math.h>

// Problem constants
#define T_STEPS 256
#define BB 8
#define NSTATE 64
#define DD 80
#define PP 256
#define HH 512
#define OO 512
#define NPARAM 161   // 2*D+1
#define PLS 171      // padded row stride for params in LDS (bank spread)
#define NEG_INF_F (-1000000.0f)

#define GSTR 88      // gemm LDS row stride in ushorts

typedef __attribute__((ext_vector_type(8))) short s16x8;
typedef __attribute__((ext_vector_type(4))) float f32x4;
typedef _Float16 h2t __attribute__((ext_vector_type(2)));

union PairU { double d; float f[2]; unsigned u[2]; };

__device__ __forceinline__ float sigmoidf_(float x) { return 1.0f / (1.0f + __expf(-x)); }
__device__ __forceinline__ unsigned short bf16rne(float x) {
  union { float f; unsigned u; } v; v.f = x;
  unsigned r = (v.u + 0x7FFFu + ((v.u >> 16) & 1u)) >> 16;
  return (unsigned short)r;
}
__device__ __forceinline__ float bf2f(unsigned s) {
  union { unsigned u; float f; } v; v.u = s << 16; return v.f;
}
__device__ __forceinline__ float fdot2_(unsigned a, unsigned b, float c) {
  union { unsigned u; h2t h; } ua, ub; ua.u = a; ub.u = b;
  return __builtin_amdgcn_fdot2(ua.h, ub.h, c, false);
}
__device__ __forceinline__ unsigned packf16(float a, float b) {
  union { unsigned u; _Float16 f[2]; } p;
  p.f[0] = (_Float16)a; p.f[1] = (_Float16)b;
  return p.u;
}

// ---------------------------------------------------------------------------
// fused conversion/prep kernel. Segments over a grand linear index:
//  s0 w_ihb   [0,524288)            bf16 linear of w_ih
//  s1 w1h16T  [524288,655360)       fp16-pair TRANSPOSED out_w1[:, :512]: [pp][o]
//  s2 w1eb    [655360,917504)       bf16 of out_w1[:, 512:1024]
//  s3 inputsb [917504,1179648)      bf16 linear of inputs
//  s4 w2b     [1179648,1245184)     bf16 linear of prenet_w2
//  s5 w1b     [1245184,1277952)     bf16 [256][128] zero-K-padded prenet_w1
//  s6 w2frag  [1277952,1376256)     MFMA B-fragments of out_w2 (verified)
//  s7 whh16   [1376256,1900544)     fp16-pair pack of w_hh rows (uint)
//  s8 hmfull  [1900544,2949120)     full-history tagged-h buffer clear (float)
//  s9 arb     [2949120,3211264)     bf16 zero-K-padded AR input [2048][128]
// ---------------------------------------------------------------------------
__global__ __launch_bounds__(256)
void conv_all(const float* __restrict__ w_ih, const float* __restrict__ out_w1,
              const float* __restrict__ inputs, const float* __restrict__ pw2,
              const float* __restrict__ pw1, const float* __restrict__ w2,
              const float* __restrict__ w_hh, const float* __restrict__ mels,
              unsigned short* __restrict__ w_ihb, unsigned* __restrict__ w1h16T,
              unsigned short* __restrict__ w1eb, unsigned short* __restrict__ inputsb,
              unsigned short* __restrict__ w2b, unsigned short* __restrict__ w1b,
              unsigned short* __restrict__ w2frag, unsigned* __restrict__ whh16,
              float* __restrict__ hmfullf, unsigned short* __restrict__ arb)
{
  int idx = blockIdx.x * 256 + threadIdx.x;
  if (idx < 524288) {
    w_ihb[idx] = bf16rne(w_ih[idx]);
  } else if (idx < 655360) {
    int i = idx - 524288; int pp = i >> 9, o = i & 511;
    w1h16T[i] = packf16(out_w1[(size_t)o * 1024 + 2 * pp],
                        out_w1[(size_t)o * 1024 + 2 * pp + 1]);
  } else if (idx < 917504) {
    int i = idx - 655360; int r = i >> 9, c = i & 511;
    w1eb[i] = bf16rne(out_w1[(size_t)r * 1024 + 512 + c]);
  } else if (idx < 1179648) {
    int i = idx - 917504;
    inputsb[i] = bf16rne(inputs[i]);
  } else if (idx < 1245184) {
    int i = idx - 1179648;
    w2b[i] = bf16rne(pw2[i]);
  } else if (idx < 1277952) {
    int i = idx - 1245184; int r = i >> 7, c = i & 127;
    w1b[i] = (c < DD) ? bf16rne(pw1[r * DD + c]) : (unsigned short)0;
  } else if (idx < 1376256) {
    int i = idx - 1277952;
    int j = i & 7, lane = (i >> 3) & 63, nt = (i >> 9) % 12, kb = i / 6144;
    int p = nt * 16 + (lane & 15);
    int o = kb * 32 + ((lane >> 4) << 3) + j;
    float v = (p < NPARAM) ? w2[p * OO + o] : 0.0f;
    w2frag[i] = bf16rne(v);
  } else if (idx < 1900544) {
    int i = idx - 1376256;                 // uint index: row*256 + pair
    int gr = i >> 8, pp = i & 255;
    const float* src = &w_hh[(size_t)gr * HH + pp * 2];
    whh16[i] = packf16(src[0], src[1]);
  } else if (idx < 2949120) {
    hmfullf[idx - 1900544] = 0.0f;         // tagged-h history clear
  } else if (idx < 3211264) {
    int i = idx - 2949120;
    int c = i & 127; int r = i >> 7; int b = r & 7; int t = r >> 3;
    float v = (t == 0 || c >= DD) ? 0.0f : mels[(b * DD + c) * T_STEPS + (t - 1)];
    arb[i] = bf16rne(v);
  }
}

// ---------------------------------------------------------------------------
// bf16 MFMA GEMM tile body (fragment conventions verified by outnet).
// ---------------------------------------------------------------------------
__device__ __forceinline__
void gemm_tile(const unsigned short* __restrict__ A, int lda,
               const unsigned short* __restrict__ B, int ldb,
               const float* __restrict__ bias1, const float* __restrict__ bias2,
               void* __restrict__ Cout, int N, int K, int relu, int obf,
               int m0, int n0, unsigned short* As, unsigned short* Bs)
{
  const int tid = threadIdx.x;
  const int lane = tid & 63, wv = tid >> 6;
  const int srow = tid >> 3, scol = (tid & 7) * 8;

  f32x4 acc[4];
#pragma unroll
  for (int m = 0; m < 4; ++m) acc[m] = (f32x4){0.f, 0.f, 0.f, 0.f};

  for (int k0 = 0; k0 < K; k0 += 64) {
    __syncthreads();
    *(float4*)&As[srow * GSTR + scol] =
        *(const float4*)&A[(size_t)(m0 + srow) * lda + k0 + scol];
    *(float4*)&As[(srow + 32) * GSTR + scol] =
        *(const float4*)&A[(size_t)(m0 + srow + 32) * lda + k0 + scol];
    *(float4*)&Bs[srow * GSTR + scol] =
        *(const float4*)&B[(size_t)(n0 + srow) * ldb + k0 + scol];
    *(float4*)&Bs[(srow + 32) * GSTR + scol] =
        *(const float4*)&B[(size_t)(n0 + srow + 32) * ldb + k0 + scol];
    __syncthreads();
#pragma unroll
    for (int ks = 0; ks < 2; ++ks) {
      const int kk = ks * 32 + 8 * (lane >> 4);
      s16x8 bfr = *(const s16x8*)&Bs[(wv * 16 + (lane & 15)) * GSTR + kk];
#pragma unroll
      for (int m = 0; m < 4; ++m) {
        s16x8 afr = *(const s16x8*)&As[(m * 16 + (lane & 15)) * GSTR + kk];
        acc[m] = __builtin_amdgcn_mfma_f32_16x16x32_bf16(afr, bfr, acc[m], 0, 0, 0);
      }
    }
  }
  const int cn = n0 + wv * 16 + (lane & 15);
  float bj = 0.f;
  if (bias1) bj += bias1[cn];
  if (bias2) bj += bias2[cn];
  const int rbase = m0 + (lane >> 4) * 4;
#pragma unroll
  for (int m = 0; m < 4; ++m)
#pragma unroll
    for (int r = 0; r < 4; ++r) {
      float v = acc[m][r] + bj;
      if (relu) v = fmaxf(v, 0.f);
      size_t ci = (size_t)(rbase + m * 16 + r) * N + cn;
      if (obf) ((unsigned short*)Cout)[ci] = bf16rne(v);
      else     ((float*)Cout)[ci] = v;
    }
}

__global__ __launch_bounds__(256)
void gemm_mfma(const unsigned short* __restrict__ A, int lda,
               const unsigned short* __restrict__ B, int ldb,
               const float* __restrict__ bias1, const float* __restrict__ bias2,
               void* __restrict__ Cout, int N, int K, int relu, int obf)
{
  __shared__ unsigned short As[64 * GSTR];
  __shared__ unsigned short Bs[64 * GSTR];
  gemm_tile(A, lda, B, ldb, bias1, bias2, Cout, N, K, relu, obf,
            blockIdx.y * 64, blockIdx.x * 64, As, Bs);
}

// merged gates (1024 blocks, 32x32 tiles) + zi (64 blocks, 8x8 tiles)
__global__ __launch_bounds__(256)
void gemm_pair(const unsigned short* __restrict__ p2b, const unsigned short* __restrict__ w_ihb,
               const float* __restrict__ b_ih, const float* __restrict__ b_hh,
               unsigned short* __restrict__ gatesb,
               const unsigned short* __restrict__ inputsb, const unsigned short* __restrict__ w1eb,
               const float* __restrict__ out_b1, float* __restrict__ zi)
{
  __shared__ unsigned short As[64 * GSTR];
  __shared__ unsigned short Bs[64 * GSTR];
  int bid = blockIdx.x;
  if (bid < 1024) {
    gemm_tile(p2b, 256, w_ihb, 256, b_ih, b_hh, gatesb, 2048, 256, 0, 1,
              (bid >> 5) * 64, (bid & 31) * 64, As, Bs);
  } else {
    int i = bid - 1024;
    gemm_tile(inputsb, 512, w1eb, 512, out_b1, nullptr, zi, 512, 512, 0, 0,
              (i >> 3) * 64, (i & 7) * 64, As, Bs);
  }
}

// ---------------------------------------------------------------------------
// MEGA kernel: 384 blocks x 512 threads.
//  blocks 0-127: LSTM producers (R9-verified structure), publishing tagged
//    {2xfp16 h, tag=t+1} words to the FULL-HISTORY buffer hmfull[t][b][256]
//    (no ring overwrite; cleared each launch by conv_all — replay-safe).
//  blocks 128-383: workers; each processes 8 (t,b) items: two-phase tagged
//    acquire of h[t,b] (R7-verified), hv matvec (fp16 fdot2, coalesced
//    w1h16T), then the verified outnet MFMA body (tid<256 active, barriers
//    wave-uniform across 512 threads). elp written with plain stores
//    (consumed by the hmm_scan kernel across a launch boundary).
// Deadlock-free: producers never wait on workers; all 384 blocks fit device
// resources simultaneously; producers are the first-dispatched blocks.
// ---------------------------------------------------------------------------
__global__ __launch_bounds__(512)
void mega(const unsigned* __restrict__ whh16, const unsigned short* __restrict__ gatesb,
          const unsigned* __restrict__ w1h16T, const float* __restrict__ zi,
          const unsigned short* __restrict__ w2frag, const float* __restrict__ b2,
          const float* __restrict__ mels, const int* __restrict__ inputs_len,
          double* __restrict__ hmfull, float* __restrict__ elp)
{
  const int tid = threadIdx.x;

  if (blockIdx.x < 128) {
    // ======================= LSTM producer role =======================
    __shared__ unsigned hl16[256];
    __shared__ float red[4][128];
    const int b = blockIdx.x & 7;
    const int s = blockIdx.x >> 3;
    const int j0 = s * 32;
    const int row = tid & 127;
    const int kq  = tid >> 7;
    const int g = row >> 5, jl = row & 31;
    const int gr = g * HH + j0 + jl;

    unsigned wreg[64];
    {
      const unsigned* wp = &whh16[(size_t)gr * 256 + kq * 64];
#pragma unroll
      for (int c = 0; c < 64; ++c) wreg[c] = wp[c];
    }
    float c_reg = 0.f;

    for (int t = 0; t < T_STEPS; ++t) {
      float gxv[4] = {0.f, 0.f, 0.f, 0.f};
      if (tid < 32) {
        const unsigned short* gp = &gatesb[((size_t)t * BB + b) * 2048 + j0 + tid];
#pragma unroll
        for (int gg = 0; gg < 4; ++gg) gxv[gg] = bf2f(gp[gg * HH]);
      }

      if (t == 0) {
        if (tid < 256) hl16[tid] = 0u;
      } else if (tid < 256) {
        const double* src = hmfull + ((size_t)(t - 1) * BB + b) * 256;
        PairU w;
        for (;;) {
          w.d = __hip_atomic_load(&src[tid], __ATOMIC_RELAXED, __HIP_MEMORY_SCOPE_AGENT);
          if (w.u[1] == (unsigned)t) break;
          __builtin_amdgcn_s_sleep(1);
        }
        hl16[tid] = w.u[0];
      }
      __syncthreads();   // barrier 1: h ready

      float a0 = 0.f, a1 = 0.f, a2 = 0.f, a3 = 0.f;
      const unsigned* hp = &hl16[kq * 64];
#pragma unroll
      for (int c = 0; c < 64; c += 4) {
        a0 = fdot2_(wreg[c + 0], hp[c + 0], a0);
        a1 = fdot2_(wreg[c + 1], hp[c + 1], a1);
        a2 = fdot2_(wreg[c + 2], hp[c + 2], a2);
        a3 = fdot2_(wreg[c + 3], hp[c + 3], a3);
      }
      red[kq][row] = (a0 + a1) + (a2 + a3);
      __syncthreads();   // barrier 2: partials ready

      if (tid < 32) {
        float iv = red[0][tid]       + red[1][tid]       + red[2][tid]       + red[3][tid]       + gxv[0];
        float fv = red[0][32 + tid]  + red[1][32 + tid]  + red[2][32 + tid]  + red[3][32 + tid]  + gxv[1];
        float gv = red[0][64 + tid]  + red[1][64 + tid]  + red[2][64 + tid]  + red[3][64 + tid]  + gxv[2];
        float ov = red[0][96 + tid]  + red[1][96 + tid]  + red[2][96 + tid]  + red[3][96 + tid]  + gxv[3];
        float ct = sigmoidf_(fv) * c_reg + sigmoidf_(iv) * tanhf(gv);
        c_reg = ct;
        float h = sigmoidf_(ov) * tanhf(ct);
        float hpart = __shfl_xor(h, 1);
        if ((tid & 1) == 0) {
          PairU pv;
          pv.u[0] = packf16(h, hpart);
          pv.u[1] = (unsigned)(t + 1);
          __hip_atomic_store(&hmfull[((size_t)t * BB + b) * 256 + s * 16 + (tid >> 1)],
                             pv.d, __ATOMIC_RELAXED, __HIP_MEMORY_SCOPE_AGENT);
        }
      }
      // no trailing barrier (R9-verified hazard analysis)
    }
    return;
  }

  // ========================== worker role ==========================
  __shared__ unsigned hl16w[256];
  __shared__ float hvs[OO];
  __shared__ float xts[96];
  __shared__ s16x8 Afr[2][256];
  __shared__ float pl[64 * PLS];

  const int wb = blockIdx.x - 128;   // 0..255

  for (int it = 0; it < 8; ++it) {
    const int item = wb + (it << 8);       // 0..2047, t ascending with it
    const int t = item >> 3, bb = item & 7;
    const double* src = hmfull + ((size_t)t * BB + bb) * 256;

    // phase A1: 16 lanes poll word-0 of each producer slice
    if (tid < 16) {
      for (;;) {
        PairU w;
        w.d = __hip_atomic_load(&src[tid * 16], __ATOMIC_RELAXED, __HIP_MEMORY_SCOPE_AGENT);
        if (__all(w.u[1] == (unsigned)(t + 1))) break;
        __builtin_amdgcn_s_sleep(1);
      }
    }
    __syncthreads();
    // phase A2: bulk tag-verified load (stragglers ~0) + xts by spare threads
    if (tid < 256) {
      PairU w;
      for (;;) {
        w.d = __hip_atomic_load(&src[tid], __ATOMIC_RELAXED, __HIP_MEMORY_SCOPE_AGENT);
        if (w.u[1] == (unsigned)(t + 1)) break;
        __builtin_amdgcn_s_sleep(1);
      }
      hl16w[tid] = w.u[0];
    } else if (tid - 256 < DD) {
      xts[tid - 256] = mels[(bb * DD + (tid - 256)) * T_STEPS + t];
    }
    __syncthreads();

    // phase B: hv matvec — all 512 threads, one output each (coalesced w1h16T)
    {
      float a0 = 0.f, a1 = 0.f, a2 = 0.f, a3 = 0.f;
#pragma unroll 8
      for (int c = 0; c < 256; c += 4) {
        a0 = fdot2_(w1h16T[(size_t)(c + 0) * 512 + tid], hl16w[c + 0], a0);
        a1 = fdot2_(w1h16T[(size_t)(c + 1) * 512 + tid], hl16w[c + 1], a1);
        a2 = fdot2_(w1h16T[(size_t)(c + 2) * 512 + tid], hl16w[c + 2], a2);
        a3 = fdot2_(w1h16T[(size_t)(c + 3) * 512 + tid], hl16w[c + 3], a3);
      }
      hvs[tid] = (a0 + a1) + (a2 + a3);
    }
    __syncthreads();

    // phase C: outnet MFMA body (tid<256 active; barriers uniform)
    const int lane = tid & 63, wv = (tid >> 6) & 3;
    const int n_state = wv * 16 + (lane & 15);
    const int osub = (lane >> 4) * 8;
    const float* zbase = zi + (size_t)(bb * 64 + n_state) * OO;

    auto genA = [&](int kb, int buf) {
      int ob = kb * 32 + osub;
      float4 z0 = *(const float4*)&zbase[ob];
      float4 z1 = *(const float4*)&zbase[ob + 4];
      float4 h0 = *(const float4*)&hvs[ob];
      float4 h1 = *(const float4*)&hvs[ob + 4];
      s16x8 s;
      s[0] = bf16rne(fmaxf(z0.x + h0.x, 0.f));
      s[1] = bf16rne(fmaxf(z0.y + h0.y, 0.f));
      s[2] = bf16rne(fmaxf(z0.z + h0.z, 0.f));
      s[3] = bf16rne(fmaxf(z0.w + h0.w, 0.f));
      s[4] = bf16rne(fmaxf(z1.x + h1.x, 0.f));
      s[5] = bf16rne(fmaxf(z1.y + h1.y, 0.f));
      s[6] = bf16rne(fmaxf(z1.z + h1.z, 0.f));
      s[7] = bf16rne(fmaxf(z1.w + h1.w, 0.f));
      Afr[buf][tid] = s;
    };

    f32x4 acc[4][3];
#pragma unroll
    for (int m = 0; m < 4; ++m)
#pragma unroll
      for (int n = 0; n < 3; ++n) acc[m][n] = (f32x4){0.f, 0.f, 0.f, 0.f};

    if (tid < 256) genA(0, 0);

    for (int kb = 0; kb < 16; ++kb) {
      __syncthreads();
      if (tid < 256) {
        const unsigned short* bfp = w2frag + ((size_t)(wv * 3) * 64 + lane) * 8;
        s16x8 bf[3];
#pragma unroll
        for (int ntl = 0; ntl < 3; ++ntl)
          bf[ntl] = *(const s16x8*)&bfp[(size_t)kb * 6144 + ntl * 512];
        if (kb < 15) genA(kb + 1, (kb + 1) & 1);
        s16x8 af[4];
#pragma unroll
        for (int m = 0; m < 4; ++m) af[m] = Afr[kb & 1][m * 64 + lane];
#pragma unroll
        for (int m = 0; m < 4; ++m)
#pragma unroll
          for (int ntl = 0; ntl < 3; ++ntl)
            acc[m][ntl] = __builtin_amdgcn_mfma_f32_16x16x32_bf16(af[m], bf[ntl], acc[m][ntl], 0, 0, 0);
      }
    }

    if (tid < 256) {
      const int prow4 = (lane >> 4) * 4;
#pragma unroll
      for (int ntl = 0; ntl < 3; ++ntl) {
        int p = (wv * 3 + ntl) * 16 + (lane & 15);
        if (p < NPARAM) {
          float bb2 = b2[p];
#pragma unroll
          for (int m = 0; m < 4; ++m)
#pragma unroll
            for (int r = 0; r < 4; ++r)
              pl[(m * 16 + prow4 + r) * PLS + p] = acc[m][ntl][r] + bb2;
        }
      }
    }
    __syncthreads();

    if (tid < 256) {
      const int ne = tid >> 2, dq = tid & 3;
      float s = 0.f;
      for (int d = dq * 20; d < dq * 20 + 20; ++d) {
        float mean = pl[ne * PLS + d];
        float sp   = pl[ne * PLS + 80 + d];
        float x = xts[d];
        float sf = (sp > 20.f) ? sp : log1pf(__expf(sp));
        float sd = fmaxf(sf, 0.001f);
        float zz = (x - mean) / sd;
        s += -0.5f * zz * zz - __logf(sd) - 0.91893853320467274f;
      }
      s += __shfl_xor(s, 1);
      s += __shfl_xor(s, 2);
      if (dq == 0) {
        int ilen = inputs_len[bb];
        float tv = pl[ne * PLS + 160];
        float4 o;
        o.x = (ne < ilen) ? s : 0.f;
        o.y = __logf(fmaxf(sigmoidf_(-tv), 1e-4f));
        o.z = __logf(fmaxf(sigmoidf_(tv), 1e-4f));
        o.w = 0.f;
        *(float4*)&elp[((size_t)item * NSTATE + ne) * 4] = o;
      }
    }
    __syncthreads();   // end-of-item: fences xts/pl for next item's phase A
  }
}

// ---------------------------------------------------------------------------
// sequential HMM forward scan — UNNORMALIZED (verified). 8 blocks, one wave
// per batch; reads elp across the launch boundary (plain stores OK).
// ---------------------------------------------------------------------------
__global__ __launch_bounds__(64)
void hmm_scan(const float* __restrict__ elp, const int* __restrict__ inputs_len,
              const int* __restrict__ mel_lens, float* __restrict__ out)
{
  const int b = blockIdx.x;
  const int n = threadIdx.x;
  const int ilen = inputs_len[b], mlen = mel_lens[b];
  const bool mask = n < ilen;
  const float4* e4 = (const float4*)elp;
  const size_t base = (size_t)b * NSTATE + n;
  float beta = 0.f, la = NEG_INF_F, llsp = 0.f;
  float4 cur = e4[base];

  for (int t = 0; t < T_STEPS; ++t) {
    float4 nxt = {0.f, 0.f, 0.f, 0.f};
    if (t + 1 < T_STEPS) nxt = e4[base + (size_t)(t + 1) * BB * NSTATE];
    float e = cur.x, ln_ = cur.y, lp_ = cur.z;
    if (t == 0) {
      beta = ((n == 0) ? 0.f : NEG_INF_F) + e;
    } else {
      float stay = beta + ln_;
      float lvs = beta + lp_;
      float lv = __shfl_up(lvs, 1, 64);
      if (n == 0) lv = NEG_INF_F;
      float mx = fmaxf(stay, lv), mn = fminf(stay, lv);
      float tt = mask ? (mx + log1pf(__expf(mn - mx))) : NEG_INF_F;
      beta = e + tt;
    }
    if (t == mlen - 1) { la = mask ? beta : NEG_INF_F; llsp = lp_; }
    cur = nxt;
  }

  float v = la + ((n == ilen - 1) ? llsp : NEG_INF_F);
  float m = v;
#pragma unroll
  for (int off = 1; off < 64; off <<= 1) m = fmaxf(m, __shfl_xor(m, off));
  float es = __expf(v - m);
#pragma unroll
  for (int off = 1; off < 64; off <<= 1) es += __shfl_xor(es, off);
  if (n == 0) out[b] = m + __logf(es);
}

// ---------------------------------------------------------------------------
extern "C" void kernel_launch(void* const* d_in, const int* in_sizes, int n_in,
                              void* d_out, int out_size, void* d_ws, size_t ws_size,
                              hipStream_t stream)
{
  const float* inputs    = (const float*)d_in[0];
  const float* mels      = (const float*)d_in[1];
  const float* prenet_w1 = (const float*)d_in[2];
  const float* prenet_w2 = (const float*)d_in[3];
  const float* w_ih      = (const float*)d_in[4];
  const float* w_hh      = (const float*)d_in[5];
  const float* b_ih      = (const float*)d_in[6];
  const float* b_hh      = (const float*)d_in[7];
  const float* out_w1    = (const float*)d_in[8];
  const float* out_b1    = (const float*)d_in[9];
  const float* out_w2    = (const float*)d_in[10];
  const float* out_b2    = (const float*)d_in[11];
  const int* inputs_len  = (const int*)d_in[12];
  const int* mel_lens    = (const int*)d_in[13];

  float* ws = (float*)d_ws;
  unsigned short* gatesb  = (unsigned short*)ws;             // 4194304 sh
  float* zi      = ws + 2097152;              // 262144 fl
  float* elp     = ws + 2359296;              // 524288 fl
  double* hmfull = (double*)(ws + 2883584);   // 524288 dbl = 1048576 fl (4MB)
  unsigned short* w2frag  = (unsigned short*)(ws + 3932160); // 98304 sh
  unsigned short* p2b     = (unsigned short*)(ws + 3981312); // 524288 sh
  unsigned short* p1b     = (unsigned short*)(ws + 4243456); // 524288 sh
  unsigned short* arb     = (unsigned short*)(ws + 4505600); // 262144 sh
  unsigned short* w1b     = (unsigned short*)(ws + 4636672); // 32768 sh
  unsigned short* w2b     = (unsigned short*)(ws + 4653056); // 65536 sh
  unsigned short* w_ihb   = (unsigned short*)(ws + 4685824); // 524288 sh
  unsigned short* w1eb    = (unsigned short*)(ws + 4947968); // 262144 sh
  unsigned short* inputsb = (unsigned short*)(ws + 5079040); // 262144 sh
  unsigned* whh16         = (unsigned*)(ws + 5210112);       // 524288 u32
  unsigned* w1h16T        = (unsigned*)(ws + 5734400);       // 131072 u32

  // fused prep — 3211264 items
  conv_all<<<12544, 256, 0, stream>>>(w_ih, out_w1, inputs, prenet_w2, prenet_w1,
                                      out_w2, w_hh, mels, w_ihb, w1h16T, w1eb,
                                      inputsb, w2b, w1b, w2frag, whh16,
                                      (float*)hmfull, arb);

  // prenet (MFMA, bf16 out)
  gemm_mfma<<<dim3(4, 32), 256, 0, stream>>>(arb, 128, w1b, 128,
                                             nullptr, nullptr, p1b, PP, 128, 1, 1);
  gemm_mfma<<<dim3(4, 32), 256, 0, stream>>>(p1b, 256, w2b, 256,
                                             nullptr, nullptr, p2b, PP, 256, 1, 1);
  // merged: gates (bf16) + zi (fp32)
  gemm_pair<<<1088, 256, 0, stream>>>(p2b, w_ihb, b_ih, b_hh, gatesb,
                                      inputsb, w1eb, out_b1, zi);

  // MEGA: LSTM producers + hv/outnet workers
  mega<<<384, 512, 0, stream>>>(whh16, gatesb, w1h16T, zi, w2frag, out_b2,
                                mels, inputs_len, hmfull, elp);

  // sequential HMM scan (unnormalized)
  hmm_scan<<<8, 64, 0, stream>>>(elp, inputs_len, mel_lens, (float*)d_out);
}

// Round 13
// 475.367 us; speedup vs baseline: 1.5498x; 1.1670x over previous
//
#include <hip/hip_runtime.h>
#include <math.h>

// Problem constants
#define T_STEPS 256
#define BB 8
#define NSTATE 64
#define DD 80
#define PP 256
#define HH 512
#define OO 512
#define NPARAM 161   // 2*D+1
#define PLS 171      // padded row stride for params in LDS (bank spread)
#define NEG_INF_F (-1000000.0f)

#define GSTR 88      // gemm LDS row stride in ushorts

typedef __attribute__((ext_vector_type(8))) short s16x8;
typedef __attribute__((ext_vector_type(4))) float f32x4;
typedef _Float16 h2t __attribute__((ext_vector_type(2)));

union PairU { double d; float f[2]; unsigned u[2]; };

__device__ __forceinline__ float sigmoidf_(float x) { return 1.0f / (1.0f + __expf(-x)); }
__device__ __forceinline__ unsigned short bf16rne(float x) {
  union { float f; unsigned u; } v; v.f = x;
  unsigned r = (v.u + 0x7FFFu + ((v.u >> 16) & 1u)) >> 16;
  return (unsigned short)r;
}
__device__ __forceinline__ float bf2f(unsigned s) {
  union { unsigned u; float f; } v; v.u = s << 16; return v.f;
}
__device__ __forceinline__ float fdot2_(unsigned a, unsigned b, float c) {
  union { unsigned u; h2t h; } ua, ub; ua.u = a; ub.u = b;
  return __builtin_amdgcn_fdot2(ua.h, ub.h, c, false);
}
__device__ __forceinline__ unsigned packf16(float a, float b) {
  union { unsigned u; _Float16 f[2]; } p;
  p.f[0] = (_Float16)a; p.f[1] = (_Float16)b;
  return p.u;
}

// ---------------------------------------------------------------------------
// fused conversion/prep kernel (clears now done by hipMemsetAsync). Segments:
//  s0 w_ihb   [0,524288)            bf16 linear of w_ih
//  s1 w1h16T  [524288,655360)       fp16-pair TRANSPOSED out_w1[:, :512]: [pp][o]
//  s2 w1eb    [655360,917504)       bf16 of out_w1[:, 512:1024]
//  s3 inputsb [917504,1179648)      bf16 linear of inputs
//  s4 w2b     [1179648,1245184)     bf16 linear of prenet_w2
//  s5 w1b     [1245184,1277952)     bf16 [256][128] zero-K-padded prenet_w1
//  s6 w2frag  [1277952,1376256)     MFMA B-fragments of out_w2 (verified)
//  s7 whh16   [1376256,1900544)     fp16-pair pack of w_hh rows (uint)
//  s8 arb     [1900544,2162688)     bf16 zero-K-padded AR input [2048][128]
// ---------------------------------------------------------------------------
__global__ __launch_bounds__(256)
void conv_all(const float* __restrict__ w_ih, const float* __restrict__ out_w1,
              const float* __restrict__ inputs, const float* __restrict__ pw2,
              const float* __restrict__ pw1, const float* __restrict__ w2,
              const float* __restrict__ w_hh, const float* __restrict__ mels,
              unsigned short* __restrict__ w_ihb, unsigned* __restrict__ w1h16T,
              unsigned short* __restrict__ w1eb, unsigned short* __restrict__ inputsb,
              unsigned short* __restrict__ w2b, unsigned short* __restrict__ w1b,
              unsigned short* __restrict__ w2frag, unsigned* __restrict__ whh16,
              unsigned short* __restrict__ arb)
{
  int idx = blockIdx.x * 256 + threadIdx.x;
  if (idx < 524288) {
    w_ihb[idx] = bf16rne(w_ih[idx]);
  } else if (idx < 655360) {
    int i = idx - 524288; int pp = i >> 9, o = i & 511;
    w1h16T[i] = packf16(out_w1[(size_t)o * 1024 + 2 * pp],
                        out_w1[(size_t)o * 1024 + 2 * pp + 1]);
  } else if (idx < 917504) {
    int i = idx - 655360; int r = i >> 9, c = i & 511;
    w1eb[i] = bf16rne(out_w1[(size_t)r * 1024 + 512 + c]);
  } else if (idx < 1179648) {
    int i = idx - 917504;
    inputsb[i] = bf16rne(inputs[i]);
  } else if (idx < 1245184) {
    int i = idx - 1179648;
    w2b[i] = bf16rne(pw2[i]);
  } else if (idx < 1277952) {
    int i = idx - 1245184; int r = i >> 7, c = i & 127;
    w1b[i] = (c < DD) ? bf16rne(pw1[r * DD + c]) : (unsigned short)0;
  } else if (idx < 1376256) {
    int i = idx - 1277952;
    int j = i & 7, lane = (i >> 3) & 63, nt = (i >> 9) % 12, kb = i / 6144;
    int p = nt * 16 + (lane & 15);
    int o = kb * 32 + ((lane >> 4) << 3) + j;
    float v = (p < NPARAM) ? w2[p * OO + o] : 0.0f;
    w2frag[i] = bf16rne(v);
  } else if (idx < 1900544) {
    int i = idx - 1376256;                 // uint index: row*256 + pair
    int gr = i >> 8, pp = i & 255;
    const float* src = &w_hh[(size_t)gr * HH + pp * 2];
    whh16[i] = packf16(src[0], src[1]);
  } else if (idx < 2162688) {
    int i = idx - 1900544;
    int c = i & 127; int r = i >> 7; int b = r & 7; int t = r >> 3;
    float v = (t == 0 || c >= DD) ? 0.0f : mels[(b * DD + c) * T_STEPS + (t - 1)];
    arb[i] = bf16rne(v);
  }
}

// ---------------------------------------------------------------------------
// bf16 MFMA GEMM tile body (fragment conventions verified by outnet).
// ---------------------------------------------------------------------------
__device__ __forceinline__
void gemm_tile(const unsigned short* __restrict__ A, int lda,
               const unsigned short* __restrict__ B, int ldb,
               const float* __restrict__ bias1, const float* __restrict__ bias2,
               void* __restrict__ Cout, int N, int K, int relu, int obf,
               int m0, int n0, unsigned short* As, unsigned short* Bs)
{
  const int tid = threadIdx.x;
  const int lane = tid & 63, wv = tid >> 6;
  const int srow = tid >> 3, scol = (tid & 7) * 8;

  f32x4 acc[4];
#pragma unroll
  for (int m = 0; m < 4; ++m) acc[m] = (f32x4){0.f, 0.f, 0.f, 0.f};

  for (int k0 = 0; k0 < K; k0 += 64) {
    __syncthreads();
    *(float4*)&As[srow * GSTR + scol] =
        *(const float4*)&A[(size_t)(m0 + srow) * lda + k0 + scol];
    *(float4*)&As[(srow + 32) * GSTR + scol] =
        *(const float4*)&A[(size_t)(m0 + srow + 32) * lda + k0 + scol];
    *(float4*)&Bs[srow * GSTR + scol] =
        *(const float4*)&B[(size_t)(n0 + srow) * ldb + k0 + scol];
    *(float4*)&Bs[(srow + 32) * GSTR + scol] =
        *(const float4*)&B[(size_t)(n0 + srow + 32) * ldb + k0 + scol];
    __syncthreads();
#pragma unroll
    for (int ks = 0; ks < 2; ++ks) {
      const int kk = ks * 32 + 8 * (lane >> 4);
      s16x8 bfr = *(const s16x8*)&Bs[(wv * 16 + (lane & 15)) * GSTR + kk];
#pragma unroll
      for (int m = 0; m < 4; ++m) {
        s16x8 afr = *(const s16x8*)&As[(m * 16 + (lane & 15)) * GSTR + kk];
        acc[m] = __builtin_amdgcn_mfma_f32_16x16x32_bf16(afr, bfr, acc[m], 0, 0, 0);
      }
    }
  }
  const int cn = n0 + wv * 16 + (lane & 15);
  float bj = 0.f;
  if (bias1) bj += bias1[cn];
  if (bias2) bj += bias2[cn];
  const int rbase = m0 + (lane >> 4) * 4;
#pragma unroll
  for (int m = 0; m < 4; ++m)
#pragma unroll
    for (int r = 0; r < 4; ++r) {
      float v = acc[m][r] + bj;
      if (relu) v = fmaxf(v, 0.f);
      size_t ci = (size_t)(rbase + m * 16 + r) * N + cn;
      if (obf) ((unsigned short*)Cout)[ci] = bf16rne(v);
      else     ((float*)Cout)[ci] = v;
    }
}

__global__ __launch_bounds__(256)
void gemm_mfma(const unsigned short* __restrict__ A, int lda,
               const unsigned short* __restrict__ B, int ldb,
               const float* __restrict__ bias1, const float* __restrict__ bias2,
               void* __restrict__ Cout, int N, int K, int relu, int obf)
{
  __shared__ unsigned short As[64 * GSTR];
  __shared__ unsigned short Bs[64 * GSTR];
  gemm_tile(A, lda, B, ldb, bias1, bias2, Cout, N, K, relu, obf,
            blockIdx.y * 64, blockIdx.x * 64, As, Bs);
}

// merged gates (1024 blocks, 32x32 tiles) + zi (64 blocks, 8x8 tiles)
__global__ __launch_bounds__(256)
void gemm_pair(const unsigned short* __restrict__ p2b, const unsigned short* __restrict__ w_ihb,
               const float* __restrict__ b_ih, const float* __restrict__ b_hh,
               unsigned short* __restrict__ gatesb,
               const unsigned short* __restrict__ inputsb, const unsigned short* __restrict__ w1eb,
               const float* __restrict__ out_b1, float* __restrict__ zi)
{
  __shared__ unsigned short As[64 * GSTR];
  __shared__ unsigned short Bs[64 * GSTR];
  int bid = blockIdx.x;
  if (bid < 1024) {
    gemm_tile(p2b, 256, w_ihb, 256, b_ih, b_hh, gatesb, 2048, 256, 0, 1,
              (bid >> 5) * 64, (bid & 31) * 64, As, Bs);
  } else {
    int i = bid - 1024;
    gemm_tile(inputsb, 512, w1eb, 512, out_b1, nullptr, zi, 512, 512, 0, 0,
              (i >> 3) * 64, (i & 7) * 64, As, Bs);
  }
}

// ---------------------------------------------------------------------------
// MEGA kernel: 385 blocks x 512 threads.
//  blocks 0-127:   LSTM producers (R9/R12-verified), tagged h -> hmfull.
//  blocks 128-383: workers: two-phase tagged h acquire, hv matvec, outnet
//    MFMA body; publish per-(t,b) emission rows as SINGLE 8B tagged words
//    elpP = {f32 em, bf16 lsn, bf16 lsp} via agent atomic store. Validity
//    tag = both bf16 sign bits set (log-sigmoid < 0 always; memset-0 =
//    invalid) — same single-word tagged-mailbox pattern as hmfull.
//  block 384:      HMM scan (unnormalized, verified): each lane polls its
//    own elpP word per t (verified acquire pattern), writes d_out.
// Deadlock-free: producers wait only on producers(t-1); workers on
// producers; hmm on workers. No cycles; 385 blocks co-resident.
// ---------------------------------------------------------------------------
__global__ __launch_bounds__(512)
void mega(const unsigned* __restrict__ whh16, const unsigned short* __restrict__ gatesb,
          const unsigned* __restrict__ w1h16T, const float* __restrict__ zi,
          const unsigned short* __restrict__ w2frag, const float* __restrict__ b2,
          const float* __restrict__ mels, const int* __restrict__ inputs_len,
          const int* __restrict__ mel_lens,
          double* __restrict__ hmfull, double* __restrict__ elpP,
          float* __restrict__ outp)
{
  const int tid = threadIdx.x;

  if (blockIdx.x < 128) {
    // ======================= LSTM producer role =======================
    __shared__ unsigned hl16[256];
    __shared__ float red[4][128];
    const int b = blockIdx.x & 7;
    const int s = blockIdx.x >> 3;
    const int j0 = s * 32;
    const int row = tid & 127;
    const int kq  = tid >> 7;
    const int g = row >> 5, jl = row & 31;
    const int gr = g * HH + j0 + jl;

    unsigned wreg[64];
    {
      const unsigned* wp = &whh16[(size_t)gr * 256 + kq * 64];
#pragma unroll
      for (int c = 0; c < 64; ++c) wreg[c] = wp[c];
    }
    float c_reg = 0.f;

    for (int t = 0; t < T_STEPS; ++t) {
      float gxv[4] = {0.f, 0.f, 0.f, 0.f};
      if (tid < 32) {
        const unsigned short* gp = &gatesb[((size_t)t * BB + b) * 2048 + j0 + tid];
#pragma unroll
        for (int gg = 0; gg < 4; ++gg) gxv[gg] = bf2f(gp[gg * HH]);
      }

      if (t == 0) {
        if (tid < 256) hl16[tid] = 0u;
      } else if (tid < 256) {
        const double* src = hmfull + ((size_t)(t - 1) * BB + b) * 256;
        PairU w;
        for (;;) {
          w.d = __hip_atomic_load(&src[tid], __ATOMIC_RELAXED, __HIP_MEMORY_SCOPE_AGENT);
          if (w.u[1] == (unsigned)t) break;
          __builtin_amdgcn_s_sleep(1);
        }
        hl16[tid] = w.u[0];
      }
      __syncthreads();   // barrier 1: h ready

      float a0 = 0.f, a1 = 0.f, a2 = 0.f, a3 = 0.f;
      const unsigned* hp = &hl16[kq * 64];
#pragma unroll
      for (int c = 0; c < 64; c += 4) {
        a0 = fdot2_(wreg[c + 0], hp[c + 0], a0);
        a1 = fdot2_(wreg[c + 1], hp[c + 1], a1);
        a2 = fdot2_(wreg[c + 2], hp[c + 2], a2);
        a3 = fdot2_(wreg[c + 3], hp[c + 3], a3);
      }
      red[kq][row] = (a0 + a1) + (a2 + a3);
      __syncthreads();   // barrier 2: partials ready

      if (tid < 32) {
        float iv = red[0][tid]       + red[1][tid]       + red[2][tid]       + red[3][tid]       + gxv[0];
        float fv = red[0][32 + tid]  + red[1][32 + tid]  + red[2][32 + tid]  + red[3][32 + tid]  + gxv[1];
        float gv = red[0][64 + tid]  + red[1][64 + tid]  + red[2][64 + tid]  + red[3][64 + tid]  + gxv[2];
        float ov = red[0][96 + tid]  + red[1][96 + tid]  + red[2][96 + tid]  + red[3][96 + tid]  + gxv[3];
        float ct = sigmoidf_(fv) * c_reg + sigmoidf_(iv) * tanhf(gv);
        c_reg = ct;
        float h = sigmoidf_(ov) * tanhf(ct);
        float hpart = __shfl_xor(h, 1);
        if ((tid & 1) == 0) {
          PairU pv;
          pv.u[0] = packf16(h, hpart);
          pv.u[1] = (unsigned)(t + 1);
          __hip_atomic_store(&hmfull[((size_t)t * BB + b) * 256 + s * 16 + (tid >> 1)],
                             pv.d, __ATOMIC_RELAXED, __HIP_MEMORY_SCOPE_AGENT);
        }
      }
      // no trailing barrier (R9-verified hazard analysis)
    }
    return;
  }

  if (blockIdx.x == 384) {
    // ========================= HMM scan role =========================
    // unnormalized recursion (verified R10/R11); lane = (b = tid>>6, n).
    const int b = tid >> 6, n = tid & 63;
    const int ilen = inputs_len[b], mlen = mel_lens[b];
    const bool mask = n < ilen;
    float beta = 0.f, la = NEG_INF_F, llsp = 0.f;

    for (int t = 0; t < T_STEPS; ++t) {
      PairU w;
      const double* src = &elpP[((size_t)t * BB + b) * NSTATE + n];
      for (;;) {
        w.d = __hip_atomic_load(src, __ATOMIC_RELAXED, __HIP_MEMORY_SCOPE_AGENT);
        if ((w.u[1] & 0x80008000u) == 0x80008000u) break;
        __builtin_amdgcn_s_sleep(1);
      }
      float e   = w.f[0];
      float ln_ = bf2f(w.u[1] & 0xFFFFu);
      float lp_ = bf2f(w.u[1] >> 16);
      if (t == 0) {
        beta = ((n == 0) ? 0.f : NEG_INF_F) + e;
      } else {
        float stay = beta + ln_;
        float lvs = beta + lp_;
        float lv = __shfl_up(lvs, 1, 64);
        if (n == 0) lv = NEG_INF_F;
        float mx = fmaxf(stay, lv), mn = fminf(stay, lv);
        float tt = mask ? (mx + log1pf(__expf(mn - mx))) : NEG_INF_F;
        beta = e + tt;
      }
      if (t == mlen - 1) { la = mask ? beta : NEG_INF_F; llsp = lp_; }
    }

    float v = la + ((n == ilen - 1) ? llsp : NEG_INF_F);
    float m = v;
#pragma unroll
    for (int off = 1; off < 64; off <<= 1) m = fmaxf(m, __shfl_xor(m, off));
    float es = __expf(v - m);
#pragma unroll
    for (int off = 1; off < 64; off <<= 1) es += __shfl_xor(es, off);
    if (n == 0) outp[b] = m + __logf(es);
    return;
  }

  // ========================== worker role ==========================
  __shared__ unsigned hl16w[256];
  __shared__ float hvs[OO];
  __shared__ float xts[96];
  __shared__ s16x8 Afr[2][256];
  __shared__ float pl[64 * PLS];

  const int wb = blockIdx.x - 128;   // 0..255

  for (int it = 0; it < 8; ++it) {
    const int item = wb + (it << 8);       // 0..2047, t ascending with it
    const int t = item >> 3, bb = item & 7;
    const double* src = hmfull + ((size_t)t * BB + bb) * 256;

    // phase A1: 16 lanes poll word-0 of each producer slice
    if (tid < 16) {
      for (;;) {
        PairU w;
        w.d = __hip_atomic_load(&src[tid * 16], __ATOMIC_RELAXED, __HIP_MEMORY_SCOPE_AGENT);
        if (__all(w.u[1] == (unsigned)(t + 1))) break;
        __builtin_amdgcn_s_sleep(1);
      }
    }
    __syncthreads();
    // phase A2: bulk tag-verified load (stragglers ~0) + xts by spare threads
    if (tid < 256) {
      PairU w;
      for (;;) {
        w.d = __hip_atomic_load(&src[tid], __ATOMIC_RELAXED, __HIP_MEMORY_SCOPE_AGENT);
        if (w.u[1] == (unsigned)(t + 1)) break;
        __builtin_amdgcn_s_sleep(1);
      }
      hl16w[tid] = w.u[0];
    } else if (tid - 256 < DD) {
      xts[tid - 256] = mels[(bb * DD + (tid - 256)) * T_STEPS + t];
    }
    __syncthreads();

    // phase B: hv matvec — all 512 threads, one output each (coalesced w1h16T)
    {
      float a0 = 0.f, a1 = 0.f, a2 = 0.f, a3 = 0.f;
#pragma unroll 8
      for (int c = 0; c < 256; c += 4) {
        a0 = fdot2_(w1h16T[(size_t)(c + 0) * 512 + tid], hl16w[c + 0], a0);
        a1 = fdot2_(w1h16T[(size_t)(c + 1) * 512 + tid], hl16w[c + 1], a1);
        a2 = fdot2_(w1h16T[(size_t)(c + 2) * 512 + tid], hl16w[c + 2], a2);
        a3 = fdot2_(w1h16T[(size_t)(c + 3) * 512 + tid], hl16w[c + 3], a3);
      }
      hvs[tid] = (a0 + a1) + (a2 + a3);
    }
    __syncthreads();

    // phase C: outnet MFMA body (tid<256 active; barriers uniform)
    const int lane = tid & 63, wv = (tid >> 6) & 3;
    const int n_state = wv * 16 + (lane & 15);
    const int osub = (lane >> 4) * 8;
    const float* zbase = zi + (size_t)(bb * 64 + n_state) * OO;

    auto genA = [&](int kb, int buf) {
      int ob = kb * 32 + osub;
      float4 z0 = *(const float4*)&zbase[ob];
      float4 z1 = *(const float4*)&zbase[ob + 4];
      float4 h0 = *(const float4*)&hvs[ob];
      float4 h1 = *(const float4*)&hvs[ob + 4];
      s16x8 s;
      s[0] = bf16rne(fmaxf(z0.x + h0.x, 0.f));
      s[1] = bf16rne(fmaxf(z0.y + h0.y, 0.f));
      s[2] = bf16rne(fmaxf(z0.z + h0.z, 0.f));
      s[3] = bf16rne(fmaxf(z0.w + h0.w, 0.f));
      s[4] = bf16rne(fmaxf(z1.x + h1.x, 0.f));
      s[5] = bf16rne(fmaxf(z1.y + h1.y, 0.f));
      s[6] = bf16rne(fmaxf(z1.z + h1.z, 0.f));
      s[7] = bf16rne(fmaxf(z1.w + h1.w, 0.f));
      Afr[buf][tid] = s;
    };

    f32x4 acc[4][3];
#pragma unroll
    for (int m = 0; m < 4; ++m)
#pragma unroll
      for (int n = 0; n < 3; ++n) acc[m][n] = (f32x4){0.f, 0.f, 0.f, 0.f};

    if (tid < 256) genA(0, 0);

    for (int kb = 0; kb < 16; ++kb) {
      __syncthreads();
      if (tid < 256) {
        const unsigned short* bfp = w2frag + ((size_t)(wv * 3) * 64 + lane) * 8;
        s16x8 bf[3];
#pragma unroll
        for (int ntl = 0; ntl < 3; ++ntl)
          bf[ntl] = *(const s16x8*)&bfp[(size_t)kb * 6144 + ntl * 512];
        if (kb < 15) genA(kb + 1, (kb + 1) & 1);
        s16x8 af[4];
#pragma unroll
        for (int m = 0; m < 4; ++m) af[m] = Afr[kb & 1][m * 64 + lane];
#pragma unroll
        for (int m = 0; m < 4; ++m)
#pragma unroll
          for (int ntl = 0; ntl < 3; ++ntl)
            acc[m][ntl] = __builtin_amdgcn_mfma_f32_16x16x32_bf16(af[m], bf[ntl], acc[m][ntl], 0, 0, 0);
      }
    }

    if (tid < 256) {
      const int prow4 = (lane >> 4) * 4;
#pragma unroll
      for (int ntl = 0; ntl < 3; ++ntl) {
        int p = (wv * 3 + ntl) * 16 + (lane & 15);
        if (p < NPARAM) {
          float bb2 = b2[p];
#pragma unroll
          for (int m = 0; m < 4; ++m)
#pragma unroll
            for (int r = 0; r < 4; ++r)
              pl[(m * 16 + prow4 + r) * PLS + p] = acc[m][ntl][r] + bb2;
        }
      }
    }
    __syncthreads();

    if (tid < 256) {
      const int ne = tid >> 2, dq = tid & 3;
      float s = 0.f;
      for (int d = dq * 20; d < dq * 20 + 20; ++d) {
        float mean = pl[ne * PLS + d];
        float sp   = pl[ne * PLS + 80 + d];
        float x = xts[d];
        float sf = (sp > 20.f) ? sp : log1pf(__expf(sp));
        float sd = fmaxf(sf, 0.001f);
        float zz = (x - mean) / sd;
        s += -0.5f * zz * zz - __logf(sd) - 0.91893853320467274f;
      }
      s += __shfl_xor(s, 1);
      s += __shfl_xor(s, 2);
      if (dq == 0) {
        int ilen = inputs_len[bb];
        float tv = pl[ne * PLS + 160];
        float lsn_ = __logf(fmaxf(sigmoidf_(-tv), 1e-4f));
        float lsp_ = __logf(fmaxf(sigmoidf_(tv), 1e-4f));
        PairU pv;
        pv.f[0] = (ne < ilen) ? s : 0.f;
        pv.u[1] = (unsigned)bf16rne(lsn_) | ((unsigned)bf16rne(lsp_) << 16);
        __hip_atomic_store(&elpP[((size_t)item) * NSTATE + ne], pv.d,
                           __ATOMIC_RELAXED, __HIP_MEMORY_SCOPE_AGENT);
      }
    }
    __syncthreads();   // end-of-item: fences xts/pl for next item's phase A
  }
}

// ---------------------------------------------------------------------------
extern "C" void kernel_launch(void* const* d_in, const int* in_sizes, int n_in,
                              void* d_out, int out_size, void* d_ws, size_t ws_size,
                              hipStream_t stream)
{
  const float* inputs    = (const float*)d_in[0];
  const float* mels      = (const float*)d_in[1];
  const float* prenet_w1 = (const float*)d_in[2];
  const float* prenet_w2 = (const float*)d_in[3];
  const float* w_ih      = (const float*)d_in[4];
  const float* w_hh      = (const float*)d_in[5];
  const float* b_ih      = (const float*)d_in[6];
  const float* b_hh      = (const float*)d_in[7];
  const float* out_w1    = (const float*)d_in[8];
  const float* out_b1    = (const float*)d_in[9];
  const float* out_w2    = (const float*)d_in[10];
  const float* out_b2    = (const float*)d_in[11];
  const int* inputs_len  = (const int*)d_in[12];
  const int* mel_lens    = (const int*)d_in[13];

  float* ws = (float*)d_ws;
  unsigned short* gatesb  = (unsigned short*)ws;             // 4194304 sh
  float* zi      = ws + 2097152;              // 262144 fl
  double* hmfull = (double*)(ws + 2359296);   // 524288 dbl (4MB)
  double* elpP   = (double*)(ws + 3407872);   // 131072 dbl (1MB) — adjacent
  unsigned short* w2frag  = (unsigned short*)(ws + 3670016); // 98304 sh
  unsigned short* p2b     = (unsigned short*)(ws + 3719168); // 524288 sh
  unsigned short* p1b     = (unsigned short*)(ws + 3981312); // 524288 sh
  unsigned short* arb     = (unsigned short*)(ws + 4243456); // 262144 sh
  unsigned short* w1b     = (unsigned short*)(ws + 4374528); // 32768 sh
  unsigned short* w2b     = (unsigned short*)(ws + 4390912); // 65536 sh
  unsigned short* w_ihb   = (unsigned short*)(ws + 4423680); // 524288 sh
  unsigned short* w1eb    = (unsigned short*)(ws + 4685824); // 262144 sh
  unsigned short* inputsb = (unsigned short*)(ws + 4816896); // 262144 sh
  unsigned* whh16         = (unsigned*)(ws + 4947968);       // 524288 u32
  unsigned* w1h16T        = (unsigned*)(ws + 5472256);       // 131072 u32

  // clear tagged buffers (hmfull 4MB + elpP 1MB, adjacent) — replay-safe
  hipMemsetAsync((void*)hmfull, 0, 5242880, stream);

  // fused prep — 2162688 items
  conv_all<<<8448, 256, 0, stream>>>(w_ih, out_w1, inputs, prenet_w2, prenet_w1,
                                     out_w2, w_hh, mels, w_ihb, w1h16T, w1eb,
                                     inputsb, w2b, w1b, w2frag, whh16, arb);

  // prenet (MFMA, bf16 out)
  gemm_mfma<<<dim3(4, 32), 256, 0, stream>>>(arb, 128, w1b, 128,
                                             nullptr, nullptr, p1b, PP, 128, 1, 1);
  gemm_mfma<<<dim3(4, 32), 256, 0, stream>>>(p1b, 256, w2b, 256,
                                             nullptr, nullptr, p2b, PP, 256, 1, 1);
  // merged: gates (bf16) + zi (fp32)
  gemm_pair<<<1088, 256, 0, stream>>>(p2b, w_ihb, b_ih, b_hh, gatesb,
                                      inputsb, w1eb, out_b1, zi);

  // MEGA: LSTM producers + hv/outnet workers + HMM scan
  mega<<<385, 512, 0, stream>>>(whh16, gatesb, w1h16T, zi, w2frag, out_b2,
                                mels, inputs_len, mel_lens, hmfull, elpP,
                                (float*)d_out);
}

// Round 14
// 453.925 us; speedup vs baseline: 1.6230x; 1.0472x over previous
//
#include <hip/hip_runtime.h>
#include <math.h>

// Problem constants
#define T_STEPS 256
#define BB 8
#define NSTATE 64
#define DD 80
#define PP 256
#define HH 512
#define OO 512
#define NPARAM 161   // 2*D+1
#define PLS 171      // padded row stride for params in LDS (bank spread)
#define NEG_INF_F (-1000000.0f)

#define GSTR 88      // gemm LDS row stride in ushorts

typedef __attribute__((ext_vector_type(8))) short s16x8;
typedef __attribute__((ext_vector_type(4))) float f32x4;
typedef _Float16 h2t __attribute__((ext_vector_type(2)));

union PairU { double d; float f[2]; unsigned u[2]; };

__device__ __forceinline__ float sigmoidf_(float x) { return 1.0f / (1.0f + __expf(-x)); }
__device__ __forceinline__ unsigned short bf16rne(float x) {
  union { float f; unsigned u; } v; v.f = x;
  unsigned r = (v.u + 0x7FFFu + ((v.u >> 16) & 1u)) >> 16;
  return (unsigned short)r;
}
__device__ __forceinline__ float bf2f(unsigned s) {
  union { unsigned u; float f; } v; v.u = s << 16; return v.f;
}
__device__ __forceinline__ float fdot2_(unsigned a, unsigned b, float c) {
  union { unsigned u; h2t h; } ua, ub; ua.u = a; ub.u = b;
  return __builtin_amdgcn_fdot2(ua.h, ub.h, c, false);
}
__device__ __forceinline__ unsigned packf16(float a, float b) {
  union { unsigned u; _Float16 f[2]; } p;
  p.f[0] = (_Float16)a; p.f[1] = (_Float16)b;
  return p.u;
}

// ---------------------------------------------------------------------------
// fused conversion/prep kernel (clears done by hipMemsetAsync). Segments:
//  s0 w_ihb   [0,524288)            bf16 linear of w_ih
//  s1 w1h16T  [524288,655360)       fp16-pair TRANSPOSED out_w1[:, :512]: [pp][o]
//  s2 w1eb    [655360,917504)       bf16 of out_w1[:, 512:1024]
//  s3 inputsb [917504,1179648)      bf16 linear of inputs
//  s4 w2b     [1179648,1245184)     bf16 linear of prenet_w2
//  s5 w1b     [1245184,1277952)     bf16 [256][128] zero-K-padded prenet_w1
//  s6 w2frag  [1277952,1376256)     MFMA B-fragments of out_w2 (verified)
//  s7 whh16   [1376256,1900544)     fp16-pair pack of w_hh rows (uint)
//  s8 arb     [1900544,2162688)     bf16 zero-K-padded AR input [2048][128]
// ---------------------------------------------------------------------------
__global__ __launch_bounds__(256)
void conv_all(const float* __restrict__ w_ih, const float* __restrict__ out_w1,
              const float* __restrict__ inputs, const float* __restrict__ pw2,
              const float* __restrict__ pw1, const float* __restrict__ w2,
              const float* __restrict__ w_hh, const float* __restrict__ mels,
              unsigned short* __restrict__ w_ihb, unsigned* __restrict__ w1h16T,
              unsigned short* __restrict__ w1eb, unsigned short* __restrict__ inputsb,
              unsigned short* __restrict__ w2b, unsigned short* __restrict__ w1b,
              unsigned short* __restrict__ w2frag, unsigned* __restrict__ whh16,
              unsigned short* __restrict__ arb)
{
  int idx = blockIdx.x * 256 + threadIdx.x;
  if (idx < 524288) {
    w_ihb[idx] = bf16rne(w_ih[idx]);
  } else if (idx < 655360) {
    int i = idx - 524288; int pp = i >> 9, o = i & 511;
    w1h16T[i] = packf16(out_w1[(size_t)o * 1024 + 2 * pp],
                        out_w1[(size_t)o * 1024 + 2 * pp + 1]);
  } else if (idx < 917504) {
    int i = idx - 655360; int r = i >> 9, c = i & 511;
    w1eb[i] = bf16rne(out_w1[(size_t)r * 1024 + 512 + c]);
  } else if (idx < 1179648) {
    int i = idx - 917504;
    inputsb[i] = bf16rne(inputs[i]);
  } else if (idx < 1245184) {
    int i = idx - 1179648;
    w2b[i] = bf16rne(pw2[i]);
  } else if (idx < 1277952) {
    int i = idx - 1245184; int r = i >> 7, c = i & 127;
    w1b[i] = (c < DD) ? bf16rne(pw1[r * DD + c]) : (unsigned short)0;
  } else if (idx < 1376256) {
    int i = idx - 1277952;
    int j = i & 7, lane = (i >> 3) & 63, nt = (i >> 9) % 12, kb = i / 6144;
    int p = nt * 16 + (lane & 15);
    int o = kb * 32 + ((lane >> 4) << 3) + j;
    float v = (p < NPARAM) ? w2[p * OO + o] : 0.0f;
    w2frag[i] = bf16rne(v);
  } else if (idx < 1900544) {
    int i = idx - 1376256;                 // uint index: row*256 + pair
    int gr = i >> 8, pp = i & 255;
    const float* src = &w_hh[(size_t)gr * HH + pp * 2];
    whh16[i] = packf16(src[0], src[1]);
  } else if (idx < 2162688) {
    int i = idx - 1900544;
    int c = i & 127; int r = i >> 7; int b = r & 7; int t = r >> 3;
    float v = (t == 0 || c >= DD) ? 0.0f : mels[(b * DD + c) * T_STEPS + (t - 1)];
    arb[i] = bf16rne(v);
  }
}

// ---------------------------------------------------------------------------
// bf16 MFMA GEMM tile body (fragment conventions verified by outnet).
// ---------------------------------------------------------------------------
__device__ __forceinline__
void gemm_tile(const unsigned short* __restrict__ A, int lda,
               const unsigned short* __restrict__ B, int ldb,
               const float* __restrict__ bias1, const float* __restrict__ bias2,
               void* __restrict__ Cout, int N, int K, int relu, int obf,
               int m0, int n0, unsigned short* As, unsigned short* Bs)
{
  const int tid = threadIdx.x;
  const int lane = tid & 63, wv = tid >> 6;
  const int srow = tid >> 3, scol = (tid & 7) * 8;

  f32x4 acc[4];
#pragma unroll
  for (int m = 0; m < 4; ++m) acc[m] = (f32x4){0.f, 0.f, 0.f, 0.f};

  for (int k0 = 0; k0 < K; k0 += 64) {
    __syncthreads();
    *(float4*)&As[srow * GSTR + scol] =
        *(const float4*)&A[(size_t)(m0 + srow) * lda + k0 + scol];
    *(float4*)&As[(srow + 32) * GSTR + scol] =
        *(const float4*)&A[(size_t)(m0 + srow + 32) * lda + k0 + scol];
    *(float4*)&Bs[srow * GSTR + scol] =
        *(const float4*)&B[(size_t)(n0 + srow) * ldb + k0 + scol];
    *(float4*)&Bs[(srow + 32) * GSTR + scol] =
        *(const float4*)&B[(size_t)(n0 + srow + 32) * ldb + k0 + scol];
    __syncthreads();
#pragma unroll
    for (int ks = 0; ks < 2; ++ks) {
      const int kk = ks * 32 + 8 * (lane >> 4);
      s16x8 bfr = *(const s16x8*)&Bs[(wv * 16 + (lane & 15)) * GSTR + kk];
#pragma unroll
      for (int m = 0; m < 4; ++m) {
        s16x8 afr = *(const s16x8*)&As[(m * 16 + (lane & 15)) * GSTR + kk];
        acc[m] = __builtin_amdgcn_mfma_f32_16x16x32_bf16(afr, bfr, acc[m], 0, 0, 0);
      }
    }
  }
  const int cn = n0 + wv * 16 + (lane & 15);
  float bj = 0.f;
  if (bias1) bj += bias1[cn];
  if (bias2) bj += bias2[cn];
  const int rbase = m0 + (lane >> 4) * 4;
#pragma unroll
  for (int m = 0; m < 4; ++m)
#pragma unroll
    for (int r = 0; r < 4; ++r) {
      float v = acc[m][r] + bj;
      if (relu) v = fmaxf(v, 0.f);
      size_t ci = (size_t)(rbase + m * 16 + r) * N + cn;
      if (obf) ((unsigned short*)Cout)[ci] = bf16rne(v);
      else     ((float*)Cout)[ci] = v;
    }
}

__global__ __launch_bounds__(256)
void gemm_mfma(const unsigned short* __restrict__ A, int lda,
               const unsigned short* __restrict__ B, int ldb,
               const float* __restrict__ bias1, const float* __restrict__ bias2,
               void* __restrict__ Cout, int N, int K, int relu, int obf)
{
  __shared__ unsigned short As[64 * GSTR];
  __shared__ unsigned short Bs[64 * GSTR];
  gemm_tile(A, lda, B, ldb, bias1, bias2, Cout, N, K, relu, obf,
            blockIdx.y * 64, blockIdx.x * 64, As, Bs);
}

// merged gates (1024 blocks, 32x32 tiles) + zi (64 blocks, 8x8 tiles)
__global__ __launch_bounds__(256)
void gemm_pair(const unsigned short* __restrict__ p2b, const unsigned short* __restrict__ w_ihb,
               const float* __restrict__ b_ih, const float* __restrict__ b_hh,
               unsigned short* __restrict__ gatesb,
               const unsigned short* __restrict__ inputsb, const unsigned short* __restrict__ w1eb,
               const float* __restrict__ out_b1, float* __restrict__ zi)
{
  __shared__ unsigned short As[64 * GSTR];
  __shared__ unsigned short Bs[64 * GSTR];
  int bid = blockIdx.x;
  if (bid < 1024) {
    gemm_tile(p2b, 256, w_ihb, 256, b_ih, b_hh, gatesb, 2048, 256, 0, 1,
              (bid >> 5) * 64, (bid & 31) * 64, As, Bs);
  } else {
    int i = bid - 1024;
    gemm_tile(inputsb, 512, w1eb, 512, out_b1, nullptr, zi, 512, 512, 0, 0,
              (i >> 3) * 64, (i & 7) * 64, As, Bs);
  }
}

// ---------------------------------------------------------------------------
// MEGA kernel: 257 blocks x 512 threads (~1 block/CU: producers get
// DEDICATED CUs — R13's 385-block config co-scheduled producers with
// workers on ~129 CUs, suspected +100µs interference).
//  blocks 0-127:   LSTM producers (R9/R12-verified), tagged h -> hmfull.
//  blocks 128-255: workers, 16 items each: two-phase tagged h acquire,
//    hv matvec, outnet MFMA; publish {f32 em, bf16 lsn, bf16 lsp} tagged
//    words (validity = both bf16 sign bits; memset-0 = invalid).
//  block 256:      HMM scan (unnormalized, verified), writes d_out.
// Deadlock-free: acyclic waits (hmm<-workers<-producers<-producers(t-1));
// 257 blocks co-resident.
// ---------------------------------------------------------------------------
__global__ __launch_bounds__(512)
void mega(const unsigned* __restrict__ whh16, const unsigned short* __restrict__ gatesb,
          const unsigned* __restrict__ w1h16T, const float* __restrict__ zi,
          const unsigned short* __restrict__ w2frag, const float* __restrict__ b2,
          const float* __restrict__ mels, const int* __restrict__ inputs_len,
          const int* __restrict__ mel_lens,
          double* __restrict__ hmfull, double* __restrict__ elpP,
          float* __restrict__ outp)
{
  const int tid = threadIdx.x;

  if (blockIdx.x < 128) {
    // ======================= LSTM producer role =======================
    __shared__ unsigned hl16[256];
    __shared__ float red[4][128];
    const int b = blockIdx.x & 7;
    const int s = blockIdx.x >> 3;
    const int j0 = s * 32;
    const int row = tid & 127;
    const int kq  = tid >> 7;
    const int g = row >> 5, jl = row & 31;
    const int gr = g * HH + j0 + jl;

    unsigned wreg[64];
    {
      const unsigned* wp = &whh16[(size_t)gr * 256 + kq * 64];
#pragma unroll
      for (int c = 0; c < 64; ++c) wreg[c] = wp[c];
    }
    float c_reg = 0.f;

    for (int t = 0; t < T_STEPS; ++t) {
      float gxv[4] = {0.f, 0.f, 0.f, 0.f};
      if (tid < 32) {
        const unsigned short* gp = &gatesb[((size_t)t * BB + b) * 2048 + j0 + tid];
#pragma unroll
        for (int gg = 0; gg < 4; ++gg) gxv[gg] = bf2f(gp[gg * HH]);
      }

      if (t == 0) {
        if (tid < 256) hl16[tid] = 0u;
      } else if (tid < 256) {
        const double* src = hmfull + ((size_t)(t - 1) * BB + b) * 256;
        PairU w;
        for (;;) {
          w.d = __hip_atomic_load(&src[tid], __ATOMIC_RELAXED, __HIP_MEMORY_SCOPE_AGENT);
          if (w.u[1] == (unsigned)t) break;
          __builtin_amdgcn_s_sleep(1);
        }
        hl16[tid] = w.u[0];
      }
      __syncthreads();   // barrier 1: h ready

      float a0 = 0.f, a1 = 0.f, a2 = 0.f, a3 = 0.f;
      const unsigned* hp = &hl16[kq * 64];
#pragma unroll
      for (int c = 0; c < 64; c += 4) {
        a0 = fdot2_(wreg[c + 0], hp[c + 0], a0);
        a1 = fdot2_(wreg[c + 1], hp[c + 1], a1);
        a2 = fdot2_(wreg[c + 2], hp[c + 2], a2);
        a3 = fdot2_(wreg[c + 3], hp[c + 3], a3);
      }
      red[kq][row] = (a0 + a1) + (a2 + a3);
      __syncthreads();   // barrier 2: partials ready

      if (tid < 32) {
        float iv = red[0][tid]       + red[1][tid]       + red[2][tid]       + red[3][tid]       + gxv[0];
        float fv = red[0][32 + tid]  + red[1][32 + tid]  + red[2][32 + tid]  + red[3][32 + tid]  + gxv[1];
        float gv = red[0][64 + tid]  + red[1][64 + tid]  + red[2][64 + tid]  + red[3][64 + tid]  + gxv[2];
        float ov = red[0][96 + tid]  + red[1][96 + tid]  + red[2][96 + tid]  + red[3][96 + tid]  + gxv[3];
        float ct = sigmoidf_(fv) * c_reg + sigmoidf_(iv) * tanhf(gv);
        c_reg = ct;
        float h = sigmoidf_(ov) * tanhf(ct);
        float hpart = __shfl_xor(h, 1);
        if ((tid & 1) == 0) {
          PairU pv;
          pv.u[0] = packf16(h, hpart);
          pv.u[1] = (unsigned)(t + 1);
          __hip_atomic_store(&hmfull[((size_t)t * BB + b) * 256 + s * 16 + (tid >> 1)],
                             pv.d, __ATOMIC_RELAXED, __HIP_MEMORY_SCOPE_AGENT);
        }
      }
      // no trailing barrier (R9-verified hazard analysis)
    }
    return;
  }

  if (blockIdx.x == 256) {
    // ========================= HMM scan role =========================
    const int b = tid >> 6, n = tid & 63;
    const int ilen = inputs_len[b], mlen = mel_lens[b];
    const bool mask = n < ilen;
    float beta = 0.f, la = NEG_INF_F, llsp = 0.f;

    for (int t = 0; t < T_STEPS; ++t) {
      PairU w;
      const double* src = &elpP[((size_t)t * BB + b) * NSTATE + n];
      for (;;) {
        w.d = __hip_atomic_load(src, __ATOMIC_RELAXED, __HIP_MEMORY_SCOPE_AGENT);
        if ((w.u[1] & 0x80008000u) == 0x80008000u) break;
        __builtin_amdgcn_s_sleep(1);
      }
      float e   = w.f[0];
      float ln_ = bf2f(w.u[1] & 0xFFFFu);
      float lp_ = bf2f(w.u[1] >> 16);
      if (t == 0) {
        beta = ((n == 0) ? 0.f : NEG_INF_F) + e;
      } else {
        float stay = beta + ln_;
        float lvs = beta + lp_;
        float lv = __shfl_up(lvs, 1, 64);
        if (n == 0) lv = NEG_INF_F;
        float mx = fmaxf(stay, lv), mn = fminf(stay, lv);
        float tt = mask ? (mx + log1pf(__expf(mn - mx))) : NEG_INF_F;
        beta = e + tt;
      }
      if (t == mlen - 1) { la = mask ? beta : NEG_INF_F; llsp = lp_; }
    }

    float v = la + ((n == ilen - 1) ? llsp : NEG_INF_F);
    float m = v;
#pragma unroll
    for (int off = 1; off < 64; off <<= 1) m = fmaxf(m, __shfl_xor(m, off));
    float es = __expf(v - m);
#pragma unroll
    for (int off = 1; off < 64; off <<= 1) es += __shfl_xor(es, off);
    if (n == 0) outp[b] = m + __logf(es);
    return;
  }

  // ========================== worker role ==========================
  __shared__ unsigned hl16w[256];
  __shared__ float hvs[OO];
  __shared__ float xts[96];
  __shared__ s16x8 Afr[2][256];
  __shared__ float pl[64 * PLS];

  const int wb = blockIdx.x - 128;   // 0..127

  for (int it = 0; it < 16; ++it) {
    const int item = wb + (it << 7);       // 0..2047, t ascending with it
    const int t = item >> 3, bb = item & 7;
    const double* src = hmfull + ((size_t)t * BB + bb) * 256;

    // phase A1: 16 lanes poll word-0 of each producer slice
    if (tid < 16) {
      for (;;) {
        PairU w;
        w.d = __hip_atomic_load(&src[tid * 16], __ATOMIC_RELAXED, __HIP_MEMORY_SCOPE_AGENT);
        if (__all(w.u[1] == (unsigned)(t + 1))) break;
        __builtin_amdgcn_s_sleep(1);
      }
    }
    __syncthreads();
    // phase A2: bulk tag-verified load (stragglers ~0) + xts by spare threads
    if (tid < 256) {
      PairU w;
      for (;;) {
        w.d = __hip_atomic_load(&src[tid], __ATOMIC_RELAXED, __HIP_MEMORY_SCOPE_AGENT);
        if (w.u[1] == (unsigned)(t + 1)) break;
        __builtin_amdgcn_s_sleep(1);
      }
      hl16w[tid] = w.u[0];
    } else if (tid - 256 < DD) {
      xts[tid - 256] = mels[(bb * DD + (tid - 256)) * T_STEPS + t];
    }
    __syncthreads();

    // phase B: hv matvec — all 512 threads, one output each (coalesced w1h16T)
    {
      float a0 = 0.f, a1 = 0.f, a2 = 0.f, a3 = 0.f;
#pragma unroll 8
      for (int c = 0; c < 256; c += 4) {
        a0 = fdot2_(w1h16T[(size_t)(c + 0) * 512 + tid], hl16w[c + 0], a0);
        a1 = fdot2_(w1h16T[(size_t)(c + 1) * 512 + tid], hl16w[c + 1], a1);
        a2 = fdot2_(w1h16T[(size_t)(c + 2) * 512 + tid], hl16w[c + 2], a2);
        a3 = fdot2_(w1h16T[(size_t)(c + 3) * 512 + tid], hl16w[c + 3], a3);
      }
      hvs[tid] = (a0 + a1) + (a2 + a3);
    }
    __syncthreads();

    // phase C: outnet MFMA body (tid<256 active; barriers uniform)
    const int lane = tid & 63, wv = (tid >> 6) & 3;
    const int n_state = wv * 16 + (lane & 15);
    const int osub = (lane >> 4) * 8;
    const float* zbase = zi + (size_t)(bb * 64 + n_state) * OO;

    auto genA = [&](int kb, int buf) {
      int ob = kb * 32 + osub;
      float4 z0 = *(const float4*)&zbase[ob];
      float4 z1 = *(const float4*)&zbase[ob + 4];
      float4 h0 = *(const float4*)&hvs[ob];
      float4 h1 = *(const float4*)&hvs[ob + 4];
      s16x8 s;
      s[0] = bf16rne(fmaxf(z0.x + h0.x, 0.f));
      s[1] = bf16rne(fmaxf(z0.y + h0.y, 0.f));
      s[2] = bf16rne(fmaxf(z0.z + h0.z, 0.f));
      s[3] = bf16rne(fmaxf(z0.w + h0.w, 0.f));
      s[4] = bf16rne(fmaxf(z1.x + h1.x, 0.f));
      s[5] = bf16rne(fmaxf(z1.y + h1.y, 0.f));
      s[6] = bf16rne(fmaxf(z1.z + h1.z, 0.f));
      s[7] = bf16rne(fmaxf(z1.w + h1.w, 0.f));
      Afr[buf][tid] = s;
    };

    f32x4 acc[4][3];
#pragma unroll
    for (int m = 0; m < 4; ++m)
#pragma unroll
      for (int n = 0; n < 3; ++n) acc[m][n] = (f32x4){0.f, 0.f, 0.f, 0.f};

    if (tid < 256) genA(0, 0);

    for (int kb = 0; kb < 16; ++kb) {
      __syncthreads();
      if (tid < 256) {
        const unsigned short* bfp = w2frag + ((size_t)(wv * 3) * 64 + lane) * 8;
        s16x8 bf[3];
#pragma unroll
        for (int ntl = 0; ntl < 3; ++ntl)
          bf[ntl] = *(const s16x8*)&bfp[(size_t)kb * 6144 + ntl * 512];
        if (kb < 15) genA(kb + 1, (kb + 1) & 1);
        s16x8 af[4];
#pragma unroll
        for (int m = 0; m < 4; ++m) af[m] = Afr[kb & 1][m * 64 + lane];
#pragma unroll
        for (int m = 0; m < 4; ++m)
#pragma unroll
          for (int ntl = 0; ntl < 3; ++ntl)
            acc[m][ntl] = __builtin_amdgcn_mfma_f32_16x16x32_bf16(af[m], bf[ntl], acc[m][ntl], 0, 0, 0);
      }
    }

    if (tid < 256) {
      const int prow4 = (lane >> 4) * 4;
#pragma unroll
      for (int ntl = 0; ntl < 3; ++ntl) {
        int p = (wv * 3 + ntl) * 16 + (lane & 15);
        if (p < NPARAM) {
          float bb2 = b2[p];
#pragma unroll
          for (int m = 0; m < 4; ++m)
#pragma unroll
            for (int r = 0; r < 4; ++r)
              pl[(m * 16 + prow4 + r) * PLS + p] = acc[m][ntl][r] + bb2;
        }
      }
    }
    __syncthreads();

    if (tid < 256) {
      const int ne = tid >> 2, dq = tid & 3;
      float s = 0.f;
      for (int d = dq * 20; d < dq * 20 + 20; ++d) {
        float mean = pl[ne * PLS + d];
        float sp   = pl[ne * PLS + 80 + d];
        float x = xts[d];
        float sf = (sp > 20.f) ? sp : log1pf(__expf(sp));
        float sd = fmaxf(sf, 0.001f);
        float zz = (x - mean) / sd;
        s += -0.5f * zz * zz - __logf(sd) - 0.91893853320467274f;
      }
      s += __shfl_xor(s, 1);
      s += __shfl_xor(s, 2);
      if (dq == 0) {
        int ilen = inputs_len[bb];
        float tv = pl[ne * PLS + 160];
        float lsn_ = __logf(fmaxf(sigmoidf_(-tv), 1e-4f));
        float lsp_ = __logf(fmaxf(sigmoidf_(tv), 1e-4f));
        PairU pv;
        pv.f[0] = (ne < ilen) ? s : 0.f;
        pv.u[1] = (unsigned)bf16rne(lsn_) | ((unsigned)bf16rne(lsp_) << 16);
        __hip_atomic_store(&elpP[((size_t)item) * NSTATE + ne], pv.d,
                           __ATOMIC_RELAXED, __HIP_MEMORY_SCOPE_AGENT);
      }
    }
    __syncthreads();   // end-of-item: fences xts/pl for next item's phase A
  }
}

// ---------------------------------------------------------------------------
extern "C" void kernel_launch(void* const* d_in, const int* in_sizes, int n_in,
                              void* d_out, int out_size, void* d_ws, size_t ws_size,
                              hipStream_t stream)
{
  const float* inputs    = (const float*)d_in[0];
  const float* mels      = (const float*)d_in[1];
  const float* prenet_w1 = (const float*)d_in[2];
  const float* prenet_w2 = (const float*)d_in[3];
  const float* w_ih      = (const float*)d_in[4];
  const float* w_hh      = (const float*)d_in[5];
  const float* b_ih      = (const float*)d_in[6];
  const float* b_hh      = (const float*)d_in[7];
  const float* out_w1    = (const float*)d_in[8];
  const float* out_b1    = (const float*)d_in[9];
  const float* out_w2    = (const float*)d_in[10];
  const float* out_b2    = (const float*)d_in[11];
  const int* inputs_len  = (const int*)d_in[12];
  const int* mel_lens    = (const int*)d_in[13];

  float* ws = (float*)d_ws;
  unsigned short* gatesb  = (unsigned short*)ws;             // 4194304 sh
  float* zi      = ws + 2097152;              // 262144 fl
  double* hmfull = (double*)(ws + 2359296);   // 524288 dbl (4MB)
  double* elpP   = (double*)(ws + 3407872);   // 131072 dbl (1MB) — adjacent
  unsigned short* w2frag  = (unsigned short*)(ws + 3670016); // 98304 sh
  unsigned short* p2b     = (unsigned short*)(ws + 3719168); // 524288 sh
  unsigned short* p1b     = (unsigned short*)(ws + 3981312); // 524288 sh
  unsigned short* arb     = (unsigned short*)(ws + 4243456); // 262144 sh
  unsigned short* w1b     = (unsigned short*)(ws + 4374528); // 32768 sh
  unsigned short* w2b     = (unsigned short*)(ws + 4390912); // 65536 sh
  unsigned short* w_ihb   = (unsigned short*)(ws + 4423680); // 524288 sh
  unsigned short* w1eb    = (unsigned short*)(ws + 4685824); // 262144 sh
  unsigned short* inputsb = (unsigned short*)(ws + 4816896); // 262144 sh
  unsigned* whh16         = (unsigned*)(ws + 4947968);       // 524288 u32
  unsigned* w1h16T        = (unsigned*)(ws + 5472256);       // 131072 u32

  // clear tagged buffers (hmfull 4MB + elpP 1MB, adjacent) — replay-safe
  hipMemsetAsync((void*)hmfull, 0, 5242880, stream);

  // fused prep — 2162688 items
  conv_all<<<8448, 256, 0, stream>>>(w_ih, out_w1, inputs, prenet_w2, prenet_w1,
                                     out_w2, w_hh, mels, w_ihb, w1h16T, w1eb,
                                     inputsb, w2b, w1b, w2frag, whh16, arb);

  // prenet (MFMA, bf16 out)
  gemm_mfma<<<dim3(4, 32), 256, 0, stream>>>(arb, 128, w1b, 128,
                                             nullptr, nullptr, p1b, PP, 128, 1, 1);
  gemm_mfma<<<dim3(4, 32), 256, 0, stream>>>(p1b, 256, w2b, 256,
                                             nullptr, nullptr, p2b, PP, 256, 1, 1);
  // merged: gates (bf16) + zi (fp32)
  gemm_pair<<<1088, 256, 0, stream>>>(p2b, w_ihb, b_ih, b_hh, gatesb,
                                      inputsb, w1eb, out_b1, zi);

  // MEGA: LSTM producers + hv/outnet workers + HMM scan (257 blocks)
  mega<<<257, 512, 0, stream>>>(whh16, gatesb, w1h16T, zi, w2frag, out_b2,
                                mels, inputs_len, mel_lens, hmfull, elpP,
                                (float*)d_out);
}